// Round 1
// baseline (517.594 us; speedup 1.0000x reference)
//
#include <hip/hip_runtime.h>
#include <hip/hip_bf16.h>

#define B_ 8
#define L_ 512
#define T_ 512
#define D_ 768
#define H_ 12
#define DH_ 64
#define SD_ 5
#define NSW_ 72   // H*(SD+1)
#define K2_ 1536  // split A:  [hi | lo]
#define K3_ 2304  // split W:  [hi | lo | hi]

typedef __attribute__((ext_vector_type(8))) short bf16x8;
typedef __attribute__((ext_vector_type(4))) float f32x4;
typedef unsigned short ushort_t;

__device__ __forceinline__ unsigned short f2bf(float x) {
    union { __hip_bfloat16 h; unsigned short u; } cv;
    cv.h = __float2bfloat16(x);
    return cv.u;
}
__device__ __forceinline__ float bf2f(unsigned short u) {
    union { unsigned short u; __hip_bfloat16 h; } cv;
    cv.u = u;
    return __bfloat162float(cv.h);
}

__device__ __forceinline__ void gload_lds16(const void* g, void* l) {
    __builtin_amdgcn_global_load_lds((const __attribute__((address_space(1))) void*)g,
                                     (__attribute__((address_space(3))) void*)l,
                                     16, 0, 0);
}

// ---------------------------------------------------------------------------
// Split fp32 activations -> A2 = [hi | lo] bf16, row-major [M][1536].
// ---------------------------------------------------------------------------
__global__ __launch_bounds__(256) void asplit_kernel(
    const float* __restrict__ q, const float* __restrict__ k, const float* __restrict__ v,
    short* __restrict__ q2, short* __restrict__ k2, short* __restrict__ v2)
{
    const int z = blockIdx.z;
    const float* A = (z == 0) ? q : (z == 1) ? k : v;
    short* O = (z == 0) ? q2 : (z == 1) ? k2 : v2;
    const int col = blockIdx.x * 256 + threadIdx.x;
    const int m   = blockIdx.y;
    if (col >= D_) return;
    const float a = A[(size_t)m * D_ + col];
    const unsigned short hi = f2bf(a);
    const unsigned short lo = f2bf(a - bf2f(hi));
    O[(size_t)m * K2_ + col]       = (short)hi;
    O[(size_t)m * K2_ + D_ + col]  = (short)lo;
}

// ---------------------------------------------------------------------------
// Transpose + split weights -> WT3 [Npad x 2304]: row n = [hi | lo | hi].
// ---------------------------------------------------------------------------
__global__ __launch_bounds__(256) void wsplit_kernel(
    const float* __restrict__ Wq, const float* __restrict__ Wk,
    const float* __restrict__ Wv, const float* __restrict__ Wl,
    const float* __restrict__ Wf,
    short* __restrict__ WqT3, short* __restrict__ WkT3, short* __restrict__ WvT3,
    short* __restrict__ WlT3, short* __restrict__ WfT3)
{
    const int z = blockIdx.z;
    const float* W; short* O; int Nw, Npad;
    if (z == 0)      { W = Wq; O = WqT3; Nw = D_;   Npad = 768; }
    else if (z == 1) { W = Wk; O = WkT3; Nw = D_;   Npad = 768; }
    else if (z == 2) { W = Wv; O = WvT3; Nw = D_;   Npad = 768; }
    else if (z == 3) { W = Wl; O = WlT3; Nw = NSW_; Npad = 128; }
    else             { W = Wf; O = WfT3; Nw = D_;   Npad = 768; }

    const int k0 = blockIdx.x * 64;
    const int n0 = blockIdx.y * 64;
    if (n0 >= Npad) return;

    __shared__ float sm[64][65];
    const int c  = threadIdx.x & 63;
    const int r4 = threadIdx.x >> 6;

#pragma unroll
    for (int i = 0; i < 16; i++) {
        const int r = i * 4 + r4;
        float val = 0.f;
        if (n0 + c < Nw) val = W[(size_t)(k0 + r) * Nw + n0 + c];
        sm[r][c] = val;
    }
    __syncthreads();

#pragma unroll
    for (int i = 0; i < 16; i++) {
        const int nl = i * 4 + r4;
        const int n  = n0 + nl;
        if (n >= Npad) continue;
        const float v = (n < Nw) ? sm[c][nl] : 0.f;
        const unsigned short hi = f2bf(v);
        const unsigned short lo = f2bf(v - bf2f(hi));
        const size_t rb = (size_t)n * K3_;
        O[rb + k0 + c]        = (short)hi;
        O[rb + 768 + k0 + c]  = (short)lo;
        O[rb + 1536 + k0 + c] = (short)hi;
    }
}

// ---------------------------------------------------------------------------
// MFMA GEMM (split-bf16, K=2304). Epilogues per z:
//  z=0: qs2a [h][b][l][hi64|lo64]   z=1: ks2a [h][b][t][hi64|lo64]
//  z=2: vt2  [h][b][dd(hi) / 64+dd(lo)][t]   z=3: swv fp32 [4096][72]
//  z=4: out fp32 [4096][768]
// ---------------------------------------------------------------------------
__global__ __launch_bounds__(256) void mfma_gemm(
    const short* __restrict__ q2, const short* __restrict__ k2, const short* __restrict__ v2,
    const short* __restrict__ WqT3, const short* __restrict__ WkT3,
    const short* __restrict__ WvT3, const short* __restrict__ WlT3,
    const short* __restrict__ WfT3,
    const float* __restrict__ bq, const float* __restrict__ bk,
    const float* __restrict__ bv, const float* __restrict__ bl,
    const float* __restrict__ bf,
    const short* __restrict__ outp2,
    ushort_t* __restrict__ qs2a, ushort_t* __restrict__ ks2a, ushort_t* __restrict__ vt2,
    float* __restrict__ swv, float* __restrict__ outf,
    int zoff)
{
    const int z = zoff + blockIdx.z;
    const short* A2; const short* WT3; const float* bias;
    if (z == 0)      { A2 = q2;    WT3 = WqT3; bias = bq; }
    else if (z == 1) { A2 = k2;    WT3 = WkT3; bias = bk; }
    else if (z == 2) { A2 = v2;    WT3 = WvT3; bias = bv; }
    else if (z == 3) { A2 = q2;    WT3 = WlT3; bias = bl; }
    else             { A2 = outp2; WT3 = WfT3; bias = bf; }

    if (z == 3 && blockIdx.x != 0) return;

    const int m0 = blockIdx.y * 128;
    const int n0 = blockIdx.x * 128;

    __shared__ __align__(16) short As[128 * 32];
    __shared__ __align__(16) short Bs[128 * 32];

    const int tid  = threadIdx.x;
    const int lane = tid & 63;
    const int wv_  = tid >> 6;
    const int wm   = (wv_ & 1) << 6;
    const int wn   = (wv_ >> 1) << 6;
    const int l15  = lane & 15;
    const int quad = lane >> 4;

    f32x4 acc[4][4] = {};

    const int sa  = tid;
    const int sb  = tid + 256;
    const int ra  = sa >> 2, ka = (sa & 3) << 3;
    const int rb  = sb >> 2, kb8 = (sb & 3) << 3;

    for (int kb = 0; kb < K3_; kb += 32) {
        const int akb = (kb < 768) ? kb : kb - 768;
        __syncthreads();
        gload_lds16(A2  + (size_t)(m0 + ra) * K2_ + akb + ka,  &As[sa << 3]);
        gload_lds16(A2  + (size_t)(m0 + rb) * K2_ + akb + kb8, &As[sb << 3]);
        gload_lds16(WT3 + (size_t)(n0 + ra) * K3_ + kb  + ka,  &Bs[sa << 3]);
        gload_lds16(WT3 + (size_t)(n0 + rb) * K3_ + kb  + kb8, &Bs[sb << 3]);
        __syncthreads();

        bf16x8 af[4], bfr[4];
#pragma unroll
        for (int t = 0; t < 4; t++) {
            af[t]  = *(const bf16x8*)&As[(wm + t * 16 + l15) * 32 + quad * 8];
            bfr[t] = *(const bf16x8*)&Bs[(wn + t * 16 + l15) * 32 + quad * 8];
        }
#pragma unroll
        for (int mt = 0; mt < 4; mt++)
#pragma unroll
            for (int nt = 0; nt < 4; nt++)
                acc[mt][nt] = __builtin_amdgcn_mfma_f32_16x16x32_bf16(
                    af[mt], bfr[nt], acc[mt][nt], 0, 0, 0);
    }

    if (z <= 2) {
        ushort_t* dst = (z == 0) ? qs2a : (z == 1) ? ks2a : vt2;
#pragma unroll
        for (int nt = 0; nt < 4; nt++) {
            const int col = n0 + wn + nt * 16 + l15;
            const int hh = col >> 6, dd = col & 63;
            const float bvv = bias[col];
#pragma unroll
            for (int mt = 0; mt < 4; mt++) {
                const int rowb = m0 + wm + mt * 16 + quad * 4;
                if (z < 2) {
#pragma unroll
                    for (int r = 0; r < 4; r++) {
                        const int gr = rowb + r;
                        const int bb = gr >> 9, ll = gr & 511;
                        const float x = acc[mt][nt][r] + bvv;
                        const ushort_t hi = f2bf(x);
                        const ushort_t lo = f2bf(x - bf2f(hi));
                        const size_t base = (((size_t)hh * B_ + bb) * 512 + ll) * 128 + dd;
                        dst[base]      = hi;
                        dst[base + 64] = lo;
                    }
                } else {
                    const int bb = rowb >> 9, tt = rowb & 511;
                    ushort_t hi4[4], lo4[4];
#pragma unroll
                    for (int r = 0; r < 4; r++) {
                        const float x = acc[mt][nt][r] + bvv;
                        hi4[r] = f2bf(x);
                        lo4[r] = f2bf(x - bf2f(hi4[r]));
                    }
                    const size_t base = (((size_t)hh * B_ + bb) * 128 + dd) * 512 + tt;
                    *(ushort4*)&dst[base]            = *(ushort4*)hi4;
                    *(ushort4*)&dst[base + 64 * 512] = *(ushort4*)lo4;
                }
            }
        }
    } else if (z == 3) {
#pragma unroll
        for (int nt = 0; nt < 4; nt++) {
            const int col = n0 + wn + nt * 16 + l15;
            if (col >= NSW_) continue;
            const float bvv = bias[col];
#pragma unroll
            for (int mt = 0; mt < 4; mt++) {
                const int row = m0 + wm + mt * 16 + quad * 4;
#pragma unroll
                for (int r = 0; r < 4; r++)
                    swv[(size_t)(row + r) * NSW_ + col] = acc[mt][nt][r] + bvv;
            }
        }
    } else {
#pragma unroll
        for (int nt = 0; nt < 4; nt++) {
            const int col = n0 + wn + nt * 16 + l15;
            const float bvv = bias[col];
#pragma unroll
            for (int mt = 0; mt < 4; mt++) {
                const int row = m0 + wm + mt * 16 + quad * 4;
#pragma unroll
                for (int r = 0; r < 4; r++)
                    outf[(size_t)(row + r) * D_ + col] = acc[mt][nt][r] + bvv;
            }
        }
    }
}

// ---------------------------------------------------------------------------
// sig16[h][b][l][t] = mask ? 0 : max(sigmoid(bias_h + w_h · ploc[b,l,t,:]), 1e-6)
// One block per (b,l): reads ploc exactly once device-wide.
// ---------------------------------------------------------------------------
__global__ __launch_bounds__(256) void sig_kernel(
    const float* __restrict__ ploc, const float* __restrict__ swv,
    const int* __restrict__ maskp, _Float16* __restrict__ sig16)
{
    const int b = blockIdx.y;
    const int l = blockIdx.x;
    const int tid = threadIdx.x;

    __shared__ float pls[512 * 5];
    __shared__ float sws[72];
    __shared__ int   msk[512];

    const float* src = ploc + (size_t)(b * 512 + l) * 512 * 5;
    for (int i = tid; i < 640; i += 256)
        *(float4*)&pls[i * 4] = *(const float4*)(src + i * 4);
    if (tid < 72) sws[tid] = swv[(size_t)(b * 512 + l) * NSW_ + tid];
    for (int i = tid; i < 512; i += 256) msk[i] = maskp[b * 512 + i];
    __syncthreads();

    for (int e = tid; e < H_ * 512; e += 256) {
        const int t  = e & 511;
        const int hh = e >> 9;
        float s = sws[hh * 6];
#pragma unroll
        for (int d = 0; d < SD_; d++) s += sws[hh * 6 + 1 + d] * pls[t * 5 + d];
        const float sig = msk[t] ? 0.f : fmaxf(1.f / (1.f + __expf(-s)), 1e-6f);
        sig16[(((size_t)hh * B_ + b) * 512 + l) * 512 + t] = (_Float16)sig;
    }
}

// ---------------------------------------------------------------------------
// MFMA attention. Block = (h, b, 64-l-tile); iterates 64-wide t-tiles.
// QK: split-bf16 3-term (K=192 effective). P -> LDS (padded) -> A-frag for PV
// (3-term vs split V^T). Row sums accumulate during the coalesced fused-store.
// ---------------------------------------------------------------------------
__global__ __launch_bounds__(256) void attn_kernel(
    const ushort_t* __restrict__ qs2, const ushort_t* __restrict__ ks2,
    const ushort_t* __restrict__ vt2, const _Float16* __restrict__ sig16,
    float* __restrict__ fused, ushort_t* __restrict__ outp2,
    float* __restrict__ sums)
{
    const int h  = blockIdx.z;
    const int b  = blockIdx.y;
    const int l0 = blockIdx.x << 6;
    const int hb = h * B_ + b;
    const int tid  = threadIdx.x;
    const int lane = tid & 63;
    const int wv   = tid >> 6;
    const int l15  = lane & 15;
    const int quad = lane >> 4;

    __shared__ __align__(16) ushort_t qs[64 * 128];
    __shared__ __align__(16) ushort_t ks[64 * 128];
    __shared__ __align__(16) ushort_t vts[128 * 64];
    __shared__ __align__(16) ushort_t ps[64 * 136];   // [l][hi 0-63 | lo 64-127 | pad]
    __shared__ float ssb[4 * 64];
    __shared__ float ssum[64];

    // stage Q tile (swizzled chunks: LDS chunk i holds global chunk (c ^ (r&7)))
    {
        const size_t qbase = ((size_t)hb * 512 + l0) * 128;
#pragma unroll
        for (int j = 0; j < 4; j++) {
            const int i = tid + 256 * j;
            const int r = i >> 4, c = i & 15, gc = c ^ (r & 7);
            gload_lds16(qs2 + qbase + r * 128 + gc * 8, &qs[i * 8]);
        }
    }

    float pacc = 0.f;
    f32x4 accpv[4] = {};

    for (int t0 = 0; t0 < T_; t0 += 64) {
        __syncthreads();
        {
            const size_t kbase = ((size_t)hb * 512 + t0) * 128;
#pragma unroll
            for (int j = 0; j < 4; j++) {
                const int i = tid + 256 * j;
                const int r = i >> 4, c = i & 15, gc = c ^ (r & 7);
                gload_lds16(ks2 + kbase + r * 128 + gc * 8, &ks[i * 8]);
            }
            const size_t vbase = (size_t)hb * 128 * 512;
#pragma unroll
            for (int j = 0; j < 4; j++) {
                const int i = tid + 256 * j;
                const int r = i >> 3, c = i & 7, gc = c ^ (r & 7);
                gload_lds16(vt2 + vbase + (size_t)r * 512 + t0 + gc * 8, &vts[i * 8]);
            }
        }
        __syncthreads();

        // prefetch sig values for this wave's 64x16 S-slice
        float sigv[4][4];
        {
            const _Float16* sgp = sig16 + (((size_t)hb * 512 + l0) * 512) + t0 + wv * 16 + l15;
#pragma unroll
            for (int mt = 0; mt < 4; mt++)
#pragma unroll
                for (int r2 = 0; r2 < 4; r2++)
                    sigv[mt][r2] = (float)sgp[(size_t)(mt * 16 + quad * 4 + r2) * 512];
        }

        // ---- QK: S[64 l x 16 t per wave] ----
        f32x4 acq[4] = {};
        {
            const int trow = wv * 16 + l15;
            const int tsw  = trow & 7;
            const bf16x8 bk0 = *(const bf16x8*)&ks[trow * 128 + ((0  + quad) ^ tsw) * 8];
            const bf16x8 bk1 = *(const bf16x8*)&ks[trow * 128 + ((4  + quad) ^ tsw) * 8];
            const bf16x8 bk2 = *(const bf16x8*)&ks[trow * 128 + ((8  + quad) ^ tsw) * 8];
            const bf16x8 bk3 = *(const bf16x8*)&ks[trow * 128 + ((12 + quad) ^ tsw) * 8];
#pragma unroll
            for (int mt = 0; mt < 4; mt++) {
                const int arow = mt * 16 + l15;
                const int asw  = arow & 7;
                const bf16x8 a0 = *(const bf16x8*)&qs[arow * 128 + ((0  + quad) ^ asw) * 8];
                const bf16x8 a1 = *(const bf16x8*)&qs[arow * 128 + ((4  + quad) ^ asw) * 8];
                const bf16x8 a2 = *(const bf16x8*)&qs[arow * 128 + ((8  + quad) ^ asw) * 8];
                const bf16x8 a3 = *(const bf16x8*)&qs[arow * 128 + ((12 + quad) ^ asw) * 8];
                f32x4 a = acq[mt];
                a = __builtin_amdgcn_mfma_f32_16x16x32_bf16(a0, bk0, a, 0, 0, 0); // hi.hi
                a = __builtin_amdgcn_mfma_f32_16x16x32_bf16(a1, bk1, a, 0, 0, 0);
                a = __builtin_amdgcn_mfma_f32_16x16x32_bf16(a0, bk2, a, 0, 0, 0); // hi.lo
                a = __builtin_amdgcn_mfma_f32_16x16x32_bf16(a1, bk3, a, 0, 0, 0);
                a = __builtin_amdgcn_mfma_f32_16x16x32_bf16(a2, bk0, a, 0, 0, 0); // lo.hi
                a = __builtin_amdgcn_mfma_f32_16x16x32_bf16(a3, bk1, a, 0, 0, 0);
                acq[mt] = a;
            }
        }

        // ---- p = sig * exp(qk/8), split to LDS ----
        {
            const int tcol = wv * 16 + l15;
#pragma unroll
            for (int mt = 0; mt < 4; mt++)
#pragma unroll
                for (int r2 = 0; r2 < 4; r2++) {
                    const int lrow = mt * 16 + quad * 4 + r2;
                    const float p  = sigv[mt][r2] * __expf(acq[mt][r2] * 0.125f);
                    const ushort_t hi = f2bf(p);
                    const ushort_t lo = f2bf(p - bf2f(hi));
                    ps[lrow * 136 + tcol]      = hi;
                    ps[lrow * 136 + 64 + tcol] = lo;
                }
        }
        __syncthreads();

        // ---- fused store (coalesced) + row-sum partials ----
        {
            const int row = tid >> 2, c4 = tid & 3;
            float vbuf[16];
            float s = 0.f;
#pragma unroll
            for (int jj = 0; jj < 16; jj++) {
                const int t = c4 * 16 + jj;
                const float pv = bf2f(ps[row * 136 + t]) + bf2f(ps[row * 136 + 64 + t]);
                vbuf[jj] = pv;
                s += pv;
            }
            pacc += s;
            float* dstf = fused + ((size_t)hb * 512 + l0 + row) * 512 + t0 + c4 * 16;
#pragma unroll
            for (int jj = 0; jj < 4; jj++)
                *(float4*)(dstf + jj * 4) = *(float4*)&vbuf[jj * 4];
        }

        // ---- PV: out[64 l x 16 d per wave] += P * V ----
        {
            const int vrh = wv * 16 + l15;
            const int vrl = 64 + vrh;
            const int swh = vrh & 7, swl = vrl & 7;
            const bf16x8 bh0 = *(const bf16x8*)&vts[vrh * 64 + ((0 + quad) ^ swh) * 8];
            const bf16x8 bh1 = *(const bf16x8*)&vts[vrh * 64 + ((4 + quad) ^ swh) * 8];
            const bf16x8 bl0 = *(const bf16x8*)&vts[vrl * 64 + ((0 + quad) ^ swl) * 8];
            const bf16x8 bl1 = *(const bf16x8*)&vts[vrl * 64 + ((4 + quad) ^ swl) * 8];
#pragma unroll
            for (int mt = 0; mt < 4; mt++) {
                const int prow = mt * 16 + l15;
                const bf16x8 ph0 = *(const bf16x8*)&ps[prow * 136 + 0  + quad * 8];
                const bf16x8 ph1 = *(const bf16x8*)&ps[prow * 136 + 32 + quad * 8];
                const bf16x8 pl0 = *(const bf16x8*)&ps[prow * 136 + 64 + quad * 8];
                const bf16x8 pl1 = *(const bf16x8*)&ps[prow * 136 + 96 + quad * 8];
                f32x4 a = accpv[mt];
                a = __builtin_amdgcn_mfma_f32_16x16x32_bf16(ph0, bh0, a, 0, 0, 0); // Phi.Vhi
                a = __builtin_amdgcn_mfma_f32_16x16x32_bf16(ph1, bh1, a, 0, 0, 0);
                a = __builtin_amdgcn_mfma_f32_16x16x32_bf16(ph0, bl0, a, 0, 0, 0); // Phi.Vlo
                a = __builtin_amdgcn_mfma_f32_16x16x32_bf16(ph1, bl1, a, 0, 0, 0);
                a = __builtin_amdgcn_mfma_f32_16x16x32_bf16(pl0, bh0, a, 0, 0, 0); // Plo.Vhi
                a = __builtin_amdgcn_mfma_f32_16x16x32_bf16(pl1, bh1, a, 0, 0, 0);
                accpv[mt] = a;
            }
        }
    }

    __syncthreads();
    ssb[(tid & 3) * 64 + (tid >> 2)] = pacc;
    __syncthreads();
    if (tid < 64) {
        const float s = ssb[tid] + ssb[64 + tid] + ssb[128 + tid] + ssb[192 + tid];
        ssum[tid] = s;
        sums[(size_t)hb * 512 + l0 + tid] = s;
    }
    __syncthreads();

#pragma unroll
    for (int mt = 0; mt < 4; mt++)
#pragma unroll
        for (int r2 = 0; r2 < 4; r2++) {
            const int lrow = mt * 16 + quad * 4 + r2;
            const float val = accpv[mt][r2] / ssum[lrow];
            const ushort_t hi = f2bf(val);
            const ushort_t lo = f2bf(val - bf2f(hi));
            const size_t obase = ((size_t)(b * 512 + l0 + lrow)) * K2_ + h * 64 + wv * 16 + l15;
            outp2[obase]       = hi;
            outp2[obase + D_]  = lo;
        }
}

// Scale fused_attn in place by 1/rowsum.
__global__ __launch_bounds__(256) void norm_kernel(
    float* __restrict__ fused, const float* __restrict__ sums)
{
    const int gi = blockIdx.x * 256 + threadIdx.x;
    float4* f4 = (float4*)fused;
    float4 v = f4[gi];
    const float inv = 1.f / sums[gi >> 7];
    v.x *= inv; v.y *= inv; v.z *= inv; v.w *= inv;
    f4[gi] = v;
}

// ---------------------------------------------------------------------------
extern "C" void kernel_launch(void* const* d_in, const int* in_sizes, int n_in,
                              void* d_out, int out_size, void* d_ws, size_t ws_size,
                              hipStream_t stream) {
    const float* q    = (const float*)d_in[0];
    const float* k    = (const float*)d_in[1];
    const float* v    = (const float*)d_in[2];
    const float* ploc = (const float*)d_in[3];
    const int*   mask = (const int*)  d_in[4];
    const float* Wq   = (const float*)d_in[5];
    const float* bq   = (const float*)d_in[6];
    const float* Wk   = (const float*)d_in[7];
    const float* bk   = (const float*)d_in[8];
    const float* Wv   = (const float*)d_in[9];
    const float* bv   = (const float*)d_in[10];
    const float* Wl   = (const float*)d_in[11];
    const float* bl   = (const float*)d_in[12];
    const float* Wf   = (const float*)d_in[13];
    const float* bf   = (const float*)d_in[14];

    // Arena. sig16 (50.33 MB) overlays [q2..WlT3 + gap] which are dead after
    // the projection GEMMs. WfT3 and later regions stay live.
    char* base = (char*)d_ws;
    short*    q2    = (short*)(base + 0);            // 12,582,912 B
    short*    k2    = (short*)(base + 12582912);
    short*    v2    = (short*)(base + 25165824);
    short*    WqT3  = (short*)(base + 37748736);     //  3,538,944 B
    short*    WkT3  = (short*)(base + 41287680);
    short*    WvT3  = (short*)(base + 44826624);
    short*    WlT3  = (short*)(base + 48365568);     //    589,824 B
    _Float16* sig16 = (_Float16*)(base + 0);         // 50,331,648 B overlay
    short*    WfT3  = (short*)(base + 50331648);
    ushort_t* qs2a  = (ushort_t*)(base + 53870592);  // 12,582,912 B
    ushort_t* ks2a  = (ushort_t*)(base + 66453504);
    ushort_t* vt2   = (ushort_t*)(base + 79036416);
    float*    swv   = (float*)(base + 91619328);     //  1,179,648 B
    float*    sums  = (float*)(base + 92798976);     //    196,608 B
    short*    outp2 = (short*)(base + 92995584);     // 12,582,912 B -> 105,578,496 total

    float* out   = (float*)d_out;
    float* fused = out + (size_t)4096 * D_;

    asplit_kernel<<<dim3(3, 4096, 3), 256, 0, stream>>>(q, k, v, q2, k2, v2);
    wsplit_kernel<<<dim3(12, 12, 5), 256, 0, stream>>>(
        Wq, Wk, Wv, Wl, Wf, WqT3, WkT3, WvT3, WlT3, WfT3);

    mfma_gemm<<<dim3(6, 32, 4), 256, 0, stream>>>(
        q2, k2, v2, WqT3, WkT3, WvT3, WlT3, WfT3,
        bq, bk, bv, bl, bf, outp2, qs2a, ks2a, vt2, swv, out, 0);

    sig_kernel<<<dim3(512, 8), 256, 0, stream>>>(ploc, swv, mask, sig16);

    attn_kernel<<<dim3(8, 8, 12), 256, 0, stream>>>(
        qs2a, ks2a, vt2, sig16, fused, (ushort_t*)outp2, sums);

    norm_kernel<<<dim3(24576), 256, 0, stream>>>(fused, sums);

    mfma_gemm<<<dim3(6, 32, 1), 256, 0, stream>>>(
        q2, k2, v2, WqT3, WkT3, WvT3, WlT3, WfT3,
        bq, bk, bv, bl, bf, outp2, qs2a, ks2a, vt2, swv, out, 4);
}

// Round 3
// 483.567 us; speedup vs baseline: 1.0704x; 1.0704x over previous
//
#include <hip/hip_runtime.h>
#include <hip/hip_bf16.h>

#define B_ 8
#define L_ 512
#define T_ 512
#define D_ 768
#define H_ 12
#define DH_ 64
#define SD_ 5
#define NSW_ 72   // H*(SD+1)
#define K2_ 1536  // split A:  [hi | lo]
#define K3_ 2304  // split W:  [hi | lo | hi]

typedef __attribute__((ext_vector_type(8))) short bf16x8;
typedef __attribute__((ext_vector_type(4))) float f32x4;
typedef unsigned short ushort_t;

__device__ __forceinline__ unsigned short f2bf(float x) {
    union { __hip_bfloat16 h; unsigned short u; } cv;
    cv.h = __float2bfloat16(x);
    return cv.u;
}
__device__ __forceinline__ float bf2f(unsigned short u) {
    union { unsigned short u; __hip_bfloat16 h; } cv;
    cv.u = u;
    return __bfloat162float(cv.h);
}

__device__ __forceinline__ void gload_lds16(const void* g, void* l) {
    __builtin_amdgcn_global_load_lds((const __attribute__((address_space(1))) void*)g,
                                     (__attribute__((address_space(3))) void*)l,
                                     16, 0, 0);
}

// ---------------------------------------------------------------------------
// Split fp32 activations -> A2 = [hi | lo] bf16, row-major [M][1536].
// ---------------------------------------------------------------------------
__global__ __launch_bounds__(256) void asplit_kernel(
    const float* __restrict__ q, const float* __restrict__ k, const float* __restrict__ v,
    short* __restrict__ q2, short* __restrict__ k2, short* __restrict__ v2)
{
    const int z = blockIdx.z;
    const float* A = (z == 0) ? q : (z == 1) ? k : v;
    short* O = (z == 0) ? q2 : (z == 1) ? k2 : v2;
    const int col = blockIdx.x * 256 + threadIdx.x;
    const int m   = blockIdx.y;
    if (col >= D_) return;
    const float a = A[(size_t)m * D_ + col];
    const unsigned short hi = f2bf(a);
    const unsigned short lo = f2bf(a - bf2f(hi));
    O[(size_t)m * K2_ + col]       = (short)hi;
    O[(size_t)m * K2_ + D_ + col]  = (short)lo;
}

// ---------------------------------------------------------------------------
// Transpose + split weights -> WT3 [Npad x 2304]: row n = [hi | lo | hi].
// ---------------------------------------------------------------------------
__global__ __launch_bounds__(256) void wsplit_kernel(
    const float* __restrict__ Wq, const float* __restrict__ Wk,
    const float* __restrict__ Wv, const float* __restrict__ Wl,
    const float* __restrict__ Wf,
    short* __restrict__ WqT3, short* __restrict__ WkT3, short* __restrict__ WvT3,
    short* __restrict__ WlT3, short* __restrict__ WfT3)
{
    const int z = blockIdx.z;
    const float* W; short* O; int Nw, Npad;
    if (z == 0)      { W = Wq; O = WqT3; Nw = D_;   Npad = 768; }
    else if (z == 1) { W = Wk; O = WkT3; Nw = D_;   Npad = 768; }
    else if (z == 2) { W = Wv; O = WvT3; Nw = D_;   Npad = 768; }
    else if (z == 3) { W = Wl; O = WlT3; Nw = NSW_; Npad = 128; }
    else             { W = Wf; O = WfT3; Nw = D_;   Npad = 768; }

    const int k0 = blockIdx.x * 64;
    const int n0 = blockIdx.y * 64;
    if (n0 >= Npad) return;

    __shared__ float sm[64][65];
    const int c  = threadIdx.x & 63;
    const int r4 = threadIdx.x >> 6;

#pragma unroll
    for (int i = 0; i < 16; i++) {
        const int r = i * 4 + r4;
        float val = 0.f;
        if (n0 + c < Nw) val = W[(size_t)(k0 + r) * Nw + n0 + c];
        sm[r][c] = val;
    }
    __syncthreads();

#pragma unroll
    for (int i = 0; i < 16; i++) {
        const int nl = i * 4 + r4;
        const int n  = n0 + nl;
        if (n >= Npad) continue;
        const float v = (n < Nw) ? sm[c][nl] : 0.f;
        const unsigned short hi = f2bf(v);
        const unsigned short lo = f2bf(v - bf2f(hi));
        const size_t rb = (size_t)n * K3_;
        O[rb + k0 + c]        = (short)hi;
        O[rb + 768 + k0 + c]  = (short)lo;
        O[rb + 1536 + k0 + c] = (short)hi;
    }
}

// ---------------------------------------------------------------------------
// MFMA GEMM (split-bf16, K=2304), BK=64, XOR-swizzled LDS (linear dest,
// pre-swizzled global source), XCD-aware block swizzle. Epilogues per z:
//  z=0: qs2a [h][b][l][hi64|lo64]   z=1: ks2a [h][b][t][hi64|lo64]
//  z=2: vt2  [h][b][dd(hi) / 64+dd(lo)][t]   z=3: swv fp32 [4096][72]
//  z=4: out fp32 [4096][768]
// ---------------------------------------------------------------------------
__global__ __launch_bounds__(256) void mfma_gemm(
    const short* __restrict__ q2, const short* __restrict__ k2, const short* __restrict__ v2,
    const short* __restrict__ WqT3, const short* __restrict__ WkT3,
    const short* __restrict__ WvT3, const short* __restrict__ WlT3,
    const short* __restrict__ WfT3,
    const float* __restrict__ bq, const float* __restrict__ bk,
    const float* __restrict__ bv, const float* __restrict__ bl,
    const float* __restrict__ bf,
    const short* __restrict__ outp2,
    ushort_t* __restrict__ qs2a, ushort_t* __restrict__ ks2a, ushort_t* __restrict__ vt2,
    float* __restrict__ swv, float* __restrict__ outf,
    int zoff)
{
    // XCD-aware bijective swizzle: co-locate the n-blocks sharing one A-panel
    // on a single XCD (nwg = 768 or 192, both % 8 == 0).
    const int nwg   = gridDim.x * gridDim.y * gridDim.z;
    const int flat  = blockIdx.x + gridDim.x * (blockIdx.y + gridDim.y * blockIdx.z);
    const int flat2 = (flat & 7) * (nwg >> 3) + (flat >> 3);
    const int bxg   = flat2 % 6;
    const int rem   = flat2 / 6;
    const int byg   = rem & 31;
    const int bzg   = rem >> 5;

    const int z = zoff + bzg;
    const short* A2; const short* WT3; const float* bias;
    if (z == 0)      { A2 = q2;    WT3 = WqT3; bias = bq; }
    else if (z == 1) { A2 = k2;    WT3 = WkT3; bias = bk; }
    else if (z == 2) { A2 = v2;    WT3 = WvT3; bias = bv; }
    else if (z == 3) { A2 = q2;    WT3 = WlT3; bias = bl; }
    else             { A2 = outp2; WT3 = WfT3; bias = bf; }

    if (z == 3 && bxg != 0) return;

    const int m0 = byg * 128;
    const int n0 = bxg * 128;

    __shared__ __align__(16) short As[128 * 64];
    __shared__ __align__(16) short Bs[128 * 64];

    const int tid  = threadIdx.x;
    const int lane = tid & 63;
    const int wv_  = tid >> 6;
    const int wm   = (wv_ & 1) << 6;
    const int wn   = (wv_ >> 1) << 6;
    const int l15  = lane & 15;
    const int quad = lane >> 4;

    f32x4 acc[4][4] = {};

    for (int kb = 0; kb < K3_; kb += 64) {
        const int akb = (kb < 768) ? kb : kb - 768;   // A2 is [hi|lo]; W row is [hi|lo|hi]
        __syncthreads();
#pragma unroll
        for (int j = 0; j < 4; j++) {
            const int i = tid + 256 * j;
            const int r = i >> 3, c = i & 7, gc = c ^ (r & 7);
            gload_lds16(A2 + (size_t)(m0 + r) * K2_ + akb + gc * 8, &As[i * 8]);
        }
#pragma unroll
        for (int j = 0; j < 4; j++) {
            const int i = tid + 256 * j;
            const int r = i >> 3, c = i & 7, gc = c ^ (r & 7);
            gload_lds16(WT3 + (size_t)(n0 + r) * K3_ + kb + gc * 8, &Bs[i * 8]);
        }
        __syncthreads();

#pragma unroll
        for (int kk = 0; kk < 2; kk++) {
            bf16x8 af[4], bfr[4];
#pragma unroll
            for (int t = 0; t < 4; t++) {
                const int ar = wm + t * 16 + l15;
                const int br = wn + t * 16 + l15;
                af[t]  = *(const bf16x8*)&As[ar * 64 + (((kk << 2) + quad) ^ (ar & 7)) * 8];
                bfr[t] = *(const bf16x8*)&Bs[br * 64 + (((kk << 2) + quad) ^ (br & 7)) * 8];
            }
#pragma unroll
            for (int mt = 0; mt < 4; mt++)
#pragma unroll
                for (int nt = 0; nt < 4; nt++)
                    acc[mt][nt] = __builtin_amdgcn_mfma_f32_16x16x32_bf16(
                        af[mt], bfr[nt], acc[mt][nt], 0, 0, 0);
        }
    }

    if (z <= 2) {
        ushort_t* dst = (z == 0) ? qs2a : (z == 1) ? ks2a : vt2;
#pragma unroll
        for (int nt = 0; nt < 4; nt++) {
            const int col = n0 + wn + nt * 16 + l15;
            const int hh = col >> 6, dd = col & 63;
            const float bvv = bias[col];
#pragma unroll
            for (int mt = 0; mt < 4; mt++) {
                const int rowb = m0 + wm + mt * 16 + quad * 4;
                if (z < 2) {
#pragma unroll
                    for (int r = 0; r < 4; r++) {
                        const int gr = rowb + r;
                        const int bb = gr >> 9, ll = gr & 511;
                        const float x = acc[mt][nt][r] + bvv;
                        const ushort_t hi = f2bf(x);
                        const ushort_t lo = f2bf(x - bf2f(hi));
                        const size_t base = (((size_t)hh * B_ + bb) * 512 + ll) * 128 + dd;
                        dst[base]      = hi;
                        dst[base + 64] = lo;
                    }
                } else {
                    const int bb = rowb >> 9, tt = rowb & 511;
                    ushort_t hi4[4], lo4[4];
#pragma unroll
                    for (int r = 0; r < 4; r++) {
                        const float x = acc[mt][nt][r] + bvv;
                        hi4[r] = f2bf(x);
                        lo4[r] = f2bf(x - bf2f(hi4[r]));
                    }
                    const size_t base = (((size_t)hh * B_ + bb) * 128 + dd) * 512 + tt;
                    *(ushort4*)&dst[base]            = *(ushort4*)hi4;
                    *(ushort4*)&dst[base + 64 * 512] = *(ushort4*)lo4;
                }
            }
        }
    } else if (z == 3) {
#pragma unroll
        for (int nt = 0; nt < 4; nt++) {
            const int col = n0 + wn + nt * 16 + l15;
            if (col >= NSW_) continue;
            const float bvv = bias[col];
#pragma unroll
            for (int mt = 0; mt < 4; mt++) {
                const int row = m0 + wm + mt * 16 + quad * 4;
#pragma unroll
                for (int r = 0; r < 4; r++)
                    swv[(size_t)(row + r) * NSW_ + col] = acc[mt][nt][r] + bvv;
            }
        }
    } else {
#pragma unroll
        for (int nt = 0; nt < 4; nt++) {
            const int col = n0 + wn + nt * 16 + l15;
            const float bvv = bias[col];
#pragma unroll
            for (int mt = 0; mt < 4; mt++) {
                const int row = m0 + wm + mt * 16 + quad * 4;
#pragma unroll
                for (int r = 0; r < 4; r++)
                    outf[(size_t)(row + r) * D_ + col] = acc[mt][nt][r] + bvv;
            }
        }
    }
}

// ---------------------------------------------------------------------------
// sig16[h][b][l][t] = mask ? 0 : max(sigmoid(bias_h + w_h · ploc[b,l,t,:]), 1e-6)
// One block per (b,l): reads ploc exactly once device-wide.
// ---------------------------------------------------------------------------
__global__ __launch_bounds__(256) void sig_kernel(
    const float* __restrict__ ploc, const float* __restrict__ swv,
    const int* __restrict__ maskp, _Float16* __restrict__ sig16)
{
    const int b = blockIdx.y;
    const int l = blockIdx.x;
    const int tid = threadIdx.x;

    __shared__ float pls[512 * 5];
    __shared__ float sws[72];
    __shared__ int   msk[512];

    const float* src = ploc + (size_t)(b * 512 + l) * 512 * 5;
    for (int i = tid; i < 640; i += 256)
        *(float4*)&pls[i * 4] = *(const float4*)(src + i * 4);
    if (tid < 72) sws[tid] = swv[(size_t)(b * 512 + l) * NSW_ + tid];
    for (int i = tid; i < 512; i += 256) msk[i] = maskp[b * 512 + i];
    __syncthreads();

    for (int e = tid; e < H_ * 512; e += 256) {
        const int t  = e & 511;
        const int hh = e >> 9;
        float s = sws[hh * 6];
#pragma unroll
        for (int d = 0; d < SD_; d++) s += sws[hh * 6 + 1 + d] * pls[t * 5 + d];
        const float sig = msk[t] ? 0.f : fmaxf(1.f / (1.f + __expf(-s)), 1e-6f);
        sig16[(((size_t)hh * B_ + b) * 512 + l) * 512 + t] = (_Float16)sig;
    }
}

// ---------------------------------------------------------------------------
// MFMA attention. Block = (h, b, 64-l-tile); iterates 64-wide t-tiles.
// QK: split-bf16 3-term (K=192 effective). P -> LDS (padded) -> A-frag for PV
// (3-term vs split V^T). Row sums accumulate during the coalesced fused-store.
// XCD-swizzled so the 8 l-tiles sharing one (h,b) K/V land on one XCD.
// ---------------------------------------------------------------------------
__global__ __launch_bounds__(256) void attn_kernel(
    const ushort_t* __restrict__ qs2, const ushort_t* __restrict__ ks2,
    const ushort_t* __restrict__ vt2, const _Float16* __restrict__ sig16,
    float* __restrict__ fused, ushort_t* __restrict__ outp2,
    float* __restrict__ sums)
{
    // grid (8,8,12) = 768 blocks; bijective XCD swizzle, x (l-tile) fastest.
    const int flat  = blockIdx.x + 8 * (blockIdx.y + 8 * blockIdx.z);
    const int flat2 = (flat & 7) * 96 + (flat >> 3);
    const int h  = flat2 / 64;
    const int b  = (flat2 >> 3) & 7;
    const int l0 = (flat2 & 7) << 6;

    const int hb = h * B_ + b;
    const int tid  = threadIdx.x;
    const int lane = tid & 63;
    const int wv   = tid >> 6;
    const int l15  = lane & 15;
    const int quad = lane >> 4;

    __shared__ __align__(16) ushort_t qs[64 * 128];
    __shared__ __align__(16) ushort_t ks[64 * 128];
    __shared__ __align__(16) ushort_t vts[128 * 64];
    __shared__ __align__(16) ushort_t ps[64 * 136];   // [l][hi 0-63 | lo 64-127 | pad]
    __shared__ float ssb[4 * 64];
    __shared__ float ssum[64];

    // stage Q tile (swizzled chunks: LDS chunk i holds global chunk (c ^ (r&7)))
    {
        const size_t qbase = ((size_t)hb * 512 + l0) * 128;
#pragma unroll
        for (int j = 0; j < 4; j++) {
            const int i = tid + 256 * j;
            const int r = i >> 4, c = i & 15, gc = c ^ (r & 7);
            gload_lds16(qs2 + qbase + r * 128 + gc * 8, &qs[i * 8]);
        }
    }

    float pacc = 0.f;
    f32x4 accpv[4] = {};

    for (int t0 = 0; t0 < T_; t0 += 64) {
        __syncthreads();
        {
            const size_t kbase = ((size_t)hb * 512 + t0) * 128;
#pragma unroll
            for (int j = 0; j < 4; j++) {
                const int i = tid + 256 * j;
                const int r = i >> 4, c = i & 15, gc = c ^ (r & 7);
                gload_lds16(ks2 + kbase + r * 128 + gc * 8, &ks[i * 8]);
            }
            const size_t vbase = (size_t)hb * 128 * 512;
#pragma unroll
            for (int j = 0; j < 4; j++) {
                const int i = tid + 256 * j;
                const int r = i >> 3, c = i & 7, gc = c ^ (r & 7);
                gload_lds16(vt2 + vbase + (size_t)r * 512 + t0 + gc * 8, &vts[i * 8]);
            }
        }
        __syncthreads();

        // prefetch sig values for this wave's 64x16 S-slice
        float sigv[4][4];
        {
            const _Float16* sgp = sig16 + (((size_t)hb * 512 + l0) * 512) + t0 + wv * 16 + l15;
#pragma unroll
            for (int mt = 0; mt < 4; mt++)
#pragma unroll
                for (int r2 = 0; r2 < 4; r2++)
                    sigv[mt][r2] = (float)sgp[(size_t)(mt * 16 + quad * 4 + r2) * 512];
        }

        // ---- QK: S[64 l x 16 t per wave] ----
        f32x4 acq[4] = {};
        {
            const int trow = wv * 16 + l15;
            const int tsw  = trow & 7;
            const bf16x8 bk0 = *(const bf16x8*)&ks[trow * 128 + ((0  + quad) ^ tsw) * 8];
            const bf16x8 bk1 = *(const bf16x8*)&ks[trow * 128 + ((4  + quad) ^ tsw) * 8];
            const bf16x8 bk2 = *(const bf16x8*)&ks[trow * 128 + ((8  + quad) ^ tsw) * 8];
            const bf16x8 bk3 = *(const bf16x8*)&ks[trow * 128 + ((12 + quad) ^ tsw) * 8];
#pragma unroll
            for (int mt = 0; mt < 4; mt++) {
                const int arow = mt * 16 + l15;
                const int asw  = arow & 7;
                const bf16x8 a0 = *(const bf16x8*)&qs[arow * 128 + ((0  + quad) ^ asw) * 8];
                const bf16x8 a1 = *(const bf16x8*)&qs[arow * 128 + ((4  + quad) ^ asw) * 8];
                const bf16x8 a2 = *(const bf16x8*)&qs[arow * 128 + ((8  + quad) ^ asw) * 8];
                const bf16x8 a3 = *(const bf16x8*)&qs[arow * 128 + ((12 + quad) ^ asw) * 8];
                f32x4 a = acq[mt];
                a = __builtin_amdgcn_mfma_f32_16x16x32_bf16(a0, bk0, a, 0, 0, 0); // hi.hi
                a = __builtin_amdgcn_mfma_f32_16x16x32_bf16(a1, bk1, a, 0, 0, 0);
                a = __builtin_amdgcn_mfma_f32_16x16x32_bf16(a0, bk2, a, 0, 0, 0); // hi.lo
                a = __builtin_amdgcn_mfma_f32_16x16x32_bf16(a1, bk3, a, 0, 0, 0);
                a = __builtin_amdgcn_mfma_f32_16x16x32_bf16(a2, bk0, a, 0, 0, 0); // lo.hi
                a = __builtin_amdgcn_mfma_f32_16x16x32_bf16(a3, bk1, a, 0, 0, 0);
                acq[mt] = a;
            }
        }

        // ---- p = sig * exp(qk/8), split to LDS ----
        {
            const int tcol = wv * 16 + l15;
#pragma unroll
            for (int mt = 0; mt < 4; mt++)
#pragma unroll
                for (int r2 = 0; r2 < 4; r2++) {
                    const int lrow = mt * 16 + quad * 4 + r2;
                    const float p  = sigv[mt][r2] * __expf(acq[mt][r2] * 0.125f);
                    const ushort_t hi = f2bf(p);
                    const ushort_t lo = f2bf(p - bf2f(hi));
                    ps[lrow * 136 + tcol]      = hi;
                    ps[lrow * 136 + 64 + tcol] = lo;
                }
        }
        __syncthreads();

        // ---- fused store (coalesced) + row-sum partials ----
        {
            const int row = tid >> 2, c4 = tid & 3;
            float vbuf[16];
            float s = 0.f;
#pragma unroll
            for (int jj = 0; jj < 16; jj++) {
                const int t = c4 * 16 + jj;
                const float pv = bf2f(ps[row * 136 + t]) + bf2f(ps[row * 136 + 64 + t]);
                vbuf[jj] = pv;
                s += pv;
            }
            pacc += s;
            float* dstf = fused + ((size_t)hb * 512 + l0 + row) * 512 + t0 + c4 * 16;
#pragma unroll
            for (int jj = 0; jj < 4; jj++)
                *(float4*)(dstf + jj * 4) = *(float4*)&vbuf[jj * 4];
        }

        // ---- PV: out[64 l x 16 d per wave] += P * V ----
        {
            const int vrh = wv * 16 + l15;
            const int vrl = 64 + vrh;
            const int swh = vrh & 7, swl = vrl & 7;
            const bf16x8 bh0 = *(const bf16x8*)&vts[vrh * 64 + ((0 + quad) ^ swh) * 8];
            const bf16x8 bh1 = *(const bf16x8*)&vts[vrh * 64 + ((4 + quad) ^ swh) * 8];
            const bf16x8 bl0 = *(const bf16x8*)&vts[vrl * 64 + ((0 + quad) ^ swl) * 8];
            const bf16x8 bl1 = *(const bf16x8*)&vts[vrl * 64 + ((4 + quad) ^ swl) * 8];
#pragma unroll
            for (int mt = 0; mt < 4; mt++) {
                const int prow = mt * 16 + l15;
                const bf16x8 ph0 = *(const bf16x8*)&ps[prow * 136 + 0  + quad * 8];
                const bf16x8 ph1 = *(const bf16x8*)&ps[prow * 136 + 32 + quad * 8];
                const bf16x8 pl0 = *(const bf16x8*)&ps[prow * 136 + 64 + quad * 8];
                const bf16x8 pl1 = *(const bf16x8*)&ps[prow * 136 + 96 + quad * 8];
                f32x4 a = accpv[mt];
                a = __builtin_amdgcn_mfma_f32_16x16x32_bf16(ph0, bh0, a, 0, 0, 0); // Phi.Vhi
                a = __builtin_amdgcn_mfma_f32_16x16x32_bf16(ph1, bh1, a, 0, 0, 0);
                a = __builtin_amdgcn_mfma_f32_16x16x32_bf16(ph0, bl0, a, 0, 0, 0); // Phi.Vlo
                a = __builtin_amdgcn_mfma_f32_16x16x32_bf16(ph1, bl1, a, 0, 0, 0);
                a = __builtin_amdgcn_mfma_f32_16x16x32_bf16(pl0, bh0, a, 0, 0, 0); // Plo.Vhi
                a = __builtin_amdgcn_mfma_f32_16x16x32_bf16(pl1, bh1, a, 0, 0, 0);
                accpv[mt] = a;
            }
        }
    }

    __syncthreads();
    ssb[(tid & 3) * 64 + (tid >> 2)] = pacc;
    __syncthreads();
    if (tid < 64) {
        const float s = ssb[tid] + ssb[64 + tid] + ssb[128 + tid] + ssb[192 + tid];
        ssum[tid] = s;
        sums[(size_t)hb * 512 + l0 + tid] = s;
    }
    __syncthreads();

#pragma unroll
    for (int mt = 0; mt < 4; mt++)
#pragma unroll
        for (int r2 = 0; r2 < 4; r2++) {
            const int lrow = mt * 16 + quad * 4 + r2;
            const float val = accpv[mt][r2] / ssum[lrow];
            const ushort_t hi = f2bf(val);
            const ushort_t lo = f2bf(val - bf2f(hi));
            const size_t obase = ((size_t)(b * 512 + l0 + lrow)) * K2_ + h * 64 + wv * 16 + l15;
            outp2[obase]       = hi;
            outp2[obase + D_]  = lo;
        }
}

// Scale fused_attn in place by 1/rowsum.
__global__ __launch_bounds__(256) void norm_kernel(
    float* __restrict__ fused, const float* __restrict__ sums)
{
    const int gi = blockIdx.x * 256 + threadIdx.x;
    float4* f4 = (float4*)fused;
    float4 v = f4[gi];
    const float inv = 1.f / sums[gi >> 7];
    v.x *= inv; v.y *= inv; v.z *= inv; v.w *= inv;
    f4[gi] = v;
}

// ---------------------------------------------------------------------------
extern "C" void kernel_launch(void* const* d_in, const int* in_sizes, int n_in,
                              void* d_out, int out_size, void* d_ws, size_t ws_size,
                              hipStream_t stream) {
    const float* q    = (const float*)d_in[0];
    const float* k    = (const float*)d_in[1];
    const float* v    = (const float*)d_in[2];
    const float* ploc = (const float*)d_in[3];
    const int*   mask = (const int*)  d_in[4];
    const float* Wq   = (const float*)d_in[5];
    const float* bq   = (const float*)d_in[6];
    const float* Wk   = (const float*)d_in[7];
    const float* bk   = (const float*)d_in[8];
    const float* Wv   = (const float*)d_in[9];
    const float* bv   = (const float*)d_in[10];
    const float* Wl   = (const float*)d_in[11];
    const float* bl   = (const float*)d_in[12];
    const float* Wf   = (const float*)d_in[13];
    const float* bf   = (const float*)d_in[14];

    // Arena. sig16 (50.33 MB) overlays [q2..WlT3 + gap] which are dead after
    // the projection GEMMs. WfT3 and later regions stay live.
    char* base = (char*)d_ws;
    short*    q2    = (short*)(base + 0);            // 12,582,912 B
    short*    k2    = (short*)(base + 12582912);
    short*    v2    = (short*)(base + 25165824);
    short*    WqT3  = (short*)(base + 37748736);     //  3,538,944 B
    short*    WkT3  = (short*)(base + 41287680);
    short*    WvT3  = (short*)(base + 44826624);
    short*    WlT3  = (short*)(base + 48365568);     //    589,824 B
    _Float16* sig16 = (_Float16*)(base + 0);         // 50,331,648 B overlay
    short*    WfT3  = (short*)(base + 50331648);
    ushort_t* qs2a  = (ushort_t*)(base + 53870592);  // 12,582,912 B
    ushort_t* ks2a  = (ushort_t*)(base + 66453504);
    ushort_t* vt2   = (ushort_t*)(base + 79036416);
    float*    swv   = (float*)(base + 91619328);     //  1,179,648 B
    float*    sums  = (float*)(base + 92798976);     //    196,608 B
    short*    outp2 = (short*)(base + 92995584);     // 12,582,912 B -> 105,578,496 total

    float* out   = (float*)d_out;
    float* fused = out + (size_t)4096 * D_;

    asplit_kernel<<<dim3(3, 4096, 3), 256, 0, stream>>>(q, k, v, q2, k2, v2);
    wsplit_kernel<<<dim3(12, 12, 5), 256, 0, stream>>>(
        Wq, Wk, Wv, Wl, Wf, WqT3, WkT3, WvT3, WlT3, WfT3);

    mfma_gemm<<<dim3(6, 32, 4), 256, 0, stream>>>(
        q2, k2, v2, WqT3, WkT3, WvT3, WlT3, WfT3,
        bq, bk, bv, bl, bf, outp2, qs2a, ks2a, vt2, swv, out, 0);

    sig_kernel<<<dim3(512, 8), 256, 0, stream>>>(ploc, swv, mask, sig16);

    attn_kernel<<<dim3(8, 8, 12), 256, 0, stream>>>(
        qs2a, ks2a, vt2, sig16, fused, (ushort_t*)outp2, sums);

    norm_kernel<<<dim3(24576), 256, 0, stream>>>(fused, sums);

    mfma_gemm<<<dim3(6, 32, 1), 256, 0, stream>>>(
        q2, k2, v2, WqT3, WkT3, WvT3, WlT3, WfT3,
        bq, bk, bv, bl, bf, outp2, qs2a, ks2a, vt2, swv, out, 4);
}

// Round 4
// 450.164 us; speedup vs baseline: 1.1498x; 1.0742x over previous
//
#include <hip/hip_runtime.h>
#include <hip/hip_bf16.h>

#define B_ 8
#define L_ 512
#define T_ 512
#define D_ 768
#define H_ 12
#define DH_ 64
#define SD_ 5
#define NSW_ 72   // H*(SD+1)
#define K2_ 1536  // split A:  [hi | lo]
#define K3_ 2304  // split W:  [hi | lo | hi]

typedef __attribute__((ext_vector_type(8))) short bf16x8;
typedef __attribute__((ext_vector_type(4))) float f32x4;
typedef unsigned short ushort_t;

__device__ __forceinline__ unsigned short f2bf(float x) {
    union { __hip_bfloat16 h; unsigned short u; } cv;
    cv.h = __float2bfloat16(x);
    return cv.u;
}
__device__ __forceinline__ float bf2f(unsigned short u) {
    union { unsigned short u; __hip_bfloat16 h; } cv;
    cv.u = u;
    return __bfloat162float(cv.h);
}

__device__ __forceinline__ void gload_lds16(const void* g, void* l) {
    __builtin_amdgcn_global_load_lds((const __attribute__((address_space(1))) void*)g,
                                     (__attribute__((address_space(3))) void*)l,
                                     16, 0, 0);
}

// ---------------------------------------------------------------------------
// Split fp32 activations -> A2 = [hi | lo] bf16, row-major [M][1536].
// ---------------------------------------------------------------------------
__global__ __launch_bounds__(256) void asplit_kernel(
    const float* __restrict__ q, const float* __restrict__ k, const float* __restrict__ v,
    short* __restrict__ q2, short* __restrict__ k2, short* __restrict__ v2)
{
    const int z = blockIdx.z;
    const float* A = (z == 0) ? q : (z == 1) ? k : v;
    short* O = (z == 0) ? q2 : (z == 1) ? k2 : v2;
    const int col = blockIdx.x * 256 + threadIdx.x;
    const int m   = blockIdx.y;
    if (col >= D_) return;
    const float a = A[(size_t)m * D_ + col];
    const unsigned short hi = f2bf(a);
    const unsigned short lo = f2bf(a - bf2f(hi));
    O[(size_t)m * K2_ + col]       = (short)hi;
    O[(size_t)m * K2_ + D_ + col]  = (short)lo;
}

// ---------------------------------------------------------------------------
// Transpose + split weights -> WT3 [Npad x 2304]: row n = [hi | lo | hi].
// ---------------------------------------------------------------------------
__global__ __launch_bounds__(256) void wsplit_kernel(
    const float* __restrict__ Wq, const float* __restrict__ Wk,
    const float* __restrict__ Wv, const float* __restrict__ Wl,
    const float* __restrict__ Wf,
    short* __restrict__ WqT3, short* __restrict__ WkT3, short* __restrict__ WvT3,
    short* __restrict__ WlT3, short* __restrict__ WfT3)
{
    const int z = blockIdx.z;
    const float* W; short* O; int Nw, Npad;
    if (z == 0)      { W = Wq; O = WqT3; Nw = D_;   Npad = 768; }
    else if (z == 1) { W = Wk; O = WkT3; Nw = D_;   Npad = 768; }
    else if (z == 2) { W = Wv; O = WvT3; Nw = D_;   Npad = 768; }
    else if (z == 3) { W = Wl; O = WlT3; Nw = NSW_; Npad = 128; }
    else             { W = Wf; O = WfT3; Nw = D_;   Npad = 768; }

    const int k0 = blockIdx.x * 64;
    const int n0 = blockIdx.y * 64;
    if (n0 >= Npad) return;

    __shared__ float sm[64][65];
    const int c  = threadIdx.x & 63;
    const int r4 = threadIdx.x >> 6;

#pragma unroll
    for (int i = 0; i < 16; i++) {
        const int r = i * 4 + r4;
        float val = 0.f;
        if (n0 + c < Nw) val = W[(size_t)(k0 + r) * Nw + n0 + c];
        sm[r][c] = val;
    }
    __syncthreads();

#pragma unroll
    for (int i = 0; i < 16; i++) {
        const int nl = i * 4 + r4;
        const int n  = n0 + nl;
        if (n >= Npad) continue;
        const float v = (n < Nw) ? sm[c][nl] : 0.f;
        const unsigned short hi = f2bf(v);
        const unsigned short lo = f2bf(v - bf2f(hi));
        const size_t rb = (size_t)n * K3_;
        O[rb + k0 + c]        = (short)hi;
        O[rb + 768 + k0 + c]  = (short)lo;
        O[rb + 1536 + k0 + c] = (short)hi;
    }
}

// ---------------------------------------------------------------------------
// MFMA GEMM (split-bf16, K=2304), BK=64, XOR-swizzled LDS, XCD block swizzle,
// 2-deep double-buffered pipeline with counted vmcnt (raw s_barrier, never
// vmcnt(0) in the main loop). Epilogues per z:
//  z=0: qs2a [h][b][l][hi64|lo64]   z=1: ks2a [h][b][t][hi64|lo64]
//  z=2: vt2  [h][b][dd(hi) / 64+dd(lo)][t]   z=3: swv fp32 [4096][72]
//  z=4: out fp32 [4096][768]
// ---------------------------------------------------------------------------
__global__ __launch_bounds__(256) void mfma_gemm(
    const short* __restrict__ q2, const short* __restrict__ k2, const short* __restrict__ v2,
    const short* __restrict__ WqT3, const short* __restrict__ WkT3,
    const short* __restrict__ WvT3, const short* __restrict__ WlT3,
    const short* __restrict__ WfT3,
    const float* __restrict__ bq, const float* __restrict__ bk,
    const float* __restrict__ bv, const float* __restrict__ bl,
    const float* __restrict__ bf,
    const short* __restrict__ outp2,
    ushort_t* __restrict__ qs2a, ushort_t* __restrict__ ks2a, ushort_t* __restrict__ vt2,
    float* __restrict__ swv, float* __restrict__ outf,
    int zoff)
{
    // XCD-aware bijective swizzle: co-locate the n-blocks sharing one A-panel
    // on a single XCD (nwg = 768 or 192, both % 8 == 0).
    const int nwg   = gridDim.x * gridDim.y * gridDim.z;
    const int flat  = blockIdx.x + gridDim.x * (blockIdx.y + gridDim.y * blockIdx.z);
    const int flat2 = (flat & 7) * (nwg >> 3) + (flat >> 3);
    const int bxg   = flat2 % 6;
    const int rem   = flat2 / 6;
    const int byg   = rem & 31;
    const int bzg   = rem >> 5;

    const int z = zoff + bzg;
    const short* A2; const short* WT3; const float* bias;
    if (z == 0)      { A2 = q2;    WT3 = WqT3; bias = bq; }
    else if (z == 1) { A2 = k2;    WT3 = WkT3; bias = bk; }
    else if (z == 2) { A2 = v2;    WT3 = WvT3; bias = bv; }
    else if (z == 3) { A2 = q2;    WT3 = WlT3; bias = bl; }
    else             { A2 = outp2; WT3 = WfT3; bias = bf; }

    if (z == 3 && bxg != 0) return;

    const int m0 = byg * 128;
    const int n0 = bxg * 128;

    __shared__ __align__(16) short As[2][128 * 64];
    __shared__ __align__(16) short Bs[2][128 * 64];

    const int tid  = threadIdx.x;
    const int lane = tid & 63;
    const int wv_  = tid >> 6;
    const int wm   = (wv_ & 1) << 6;
    const int wn   = (wv_ >> 1) << 6;
    const int l15  = lane & 15;
    const int quad = lane >> 4;

    f32x4 acc[4][4] = {};

    const int NT = K3_ / 64;   // 36 K-steps

    // Stage one BK=64 tile (8 gload_lds / thread: 4 A + 4 B) into buffer buf.
    auto stage = [&](int buf, int kb) {
        const int akb = (kb < 768) ? kb : kb - 768;  // A=[hi|lo]; W=[hi|lo|hi]
#pragma unroll
        for (int j = 0; j < 4; j++) {
            const int i = tid + 256 * j;
            const int r = i >> 3, c = i & 7, gc = c ^ (r & 7);
            gload_lds16(A2 + (size_t)(m0 + r) * K2_ + akb + gc * 8, &As[buf][i * 8]);
        }
#pragma unroll
        for (int j = 0; j < 4; j++) {
            const int i = tid + 256 * j;
            const int r = i >> 3, c = i & 7, gc = c ^ (r & 7);
            gload_lds16(WT3 + (size_t)(n0 + r) * K3_ + kb + gc * 8, &Bs[buf][i * 8]);
        }
    };

    // Prologue: tiles 0 and 1 in flight (16 outstanding loads / thread).
    stage(0, 0);
    stage(1, 64);

    int cur = 0;
    for (int t = 0; t < NT; ++t) {
        // Wait only for the oldest 8 loads (tile t); tile t+1 stays in flight.
        asm volatile("s_waitcnt vmcnt(8)" ::: "memory");
        __builtin_amdgcn_s_barrier();

        bf16x8 af[2][4], bfr[2][4];
#pragma unroll
        for (int kk = 0; kk < 2; kk++)
#pragma unroll
            for (int tt = 0; tt < 4; tt++) {
                const int ar = wm + tt * 16 + l15;
                const int br = wn + tt * 16 + l15;
                af[kk][tt]  = *(const bf16x8*)&As[cur][ar * 64 + (((kk << 2) + quad) ^ (ar & 7)) * 8];
                bfr[kk][tt] = *(const bf16x8*)&Bs[cur][br * 64 + (((kk << 2) + quad) ^ (br & 7)) * 8];
            }
        // All LDS reads done (this wave), then all waves -> safe to overwrite.
        asm volatile("s_waitcnt lgkmcnt(0)" ::: "memory");
        __builtin_amdgcn_sched_barrier(0);
        __builtin_amdgcn_s_barrier();

        // Re-stage the just-consumed buffer with tile t+2 (dummy-wrap in the
        // tail keeps the vmcnt accounting uniform; those loads are never read).
        const int kb2 = (t + 2 < NT) ? (t + 2) * 64 : 0;
        stage(cur, kb2);
        __builtin_amdgcn_sched_barrier(0);

#pragma unroll
        for (int kk = 0; kk < 2; kk++)
#pragma unroll
            for (int mt = 0; mt < 4; mt++)
#pragma unroll
                for (int nt = 0; nt < 4; nt++)
                    acc[mt][nt] = __builtin_amdgcn_mfma_f32_16x16x32_bf16(
                        af[kk][mt], bfr[kk][nt], acc[mt][nt], 0, 0, 0);
        cur ^= 1;
    }
    // Drain trailing dummy loads before the wave can exit / reuse LDS.
    asm volatile("s_waitcnt vmcnt(0)" ::: "memory");

    if (z <= 2) {
        ushort_t* dst = (z == 0) ? qs2a : (z == 1) ? ks2a : vt2;
#pragma unroll
        for (int nt = 0; nt < 4; nt++) {
            const int col = n0 + wn + nt * 16 + l15;
            const int hh = col >> 6, dd = col & 63;
            const float bvv = bias[col];
#pragma unroll
            for (int mt = 0; mt < 4; mt++) {
                const int rowb = m0 + wm + mt * 16 + quad * 4;
                if (z < 2) {
#pragma unroll
                    for (int r = 0; r < 4; r++) {
                        const int gr = rowb + r;
                        const int bb = gr >> 9, ll = gr & 511;
                        const float x = acc[mt][nt][r] + bvv;
                        const ushort_t hi = f2bf(x);
                        const ushort_t lo = f2bf(x - bf2f(hi));
                        const size_t base = (((size_t)hh * B_ + bb) * 512 + ll) * 128 + dd;
                        dst[base]      = hi;
                        dst[base + 64] = lo;
                    }
                } else {
                    const int bb = rowb >> 9, tt = rowb & 511;
                    ushort_t hi4[4], lo4[4];
#pragma unroll
                    for (int r = 0; r < 4; r++) {
                        const float x = acc[mt][nt][r] + bvv;
                        hi4[r] = f2bf(x);
                        lo4[r] = f2bf(x - bf2f(hi4[r]));
                    }
                    const size_t base = (((size_t)hh * B_ + bb) * 128 + dd) * 512 + tt;
                    *(ushort4*)&dst[base]            = *(ushort4*)hi4;
                    *(ushort4*)&dst[base + 64 * 512] = *(ushort4*)lo4;
                }
            }
        }
    } else if (z == 3) {
#pragma unroll
        for (int nt = 0; nt < 4; nt++) {
            const int col = n0 + wn + nt * 16 + l15;
            if (col >= NSW_) continue;
            const float bvv = bias[col];
#pragma unroll
            for (int mt = 0; mt < 4; mt++) {
                const int row = m0 + wm + mt * 16 + quad * 4;
#pragma unroll
                for (int r = 0; r < 4; r++)
                    swv[(size_t)(row + r) * NSW_ + col] = acc[mt][nt][r] + bvv;
            }
        }
    } else {
#pragma unroll
        for (int nt = 0; nt < 4; nt++) {
            const int col = n0 + wn + nt * 16 + l15;
            const float bvv = bias[col];
#pragma unroll
            for (int mt = 0; mt < 4; mt++) {
                const int row = m0 + wm + mt * 16 + quad * 4;
#pragma unroll
                for (int r = 0; r < 4; r++)
                    outf[(size_t)(row + r) * D_ + col] = acc[mt][nt][r] + bvv;
            }
        }
    }
}

// ---------------------------------------------------------------------------
// sig16[h][b][l][t] = mask ? 0 : max(sigmoid(bias_h + w_h · ploc[b,l,t,:]), 1e-6)
// One block per (b,l): reads ploc exactly once device-wide.
// ---------------------------------------------------------------------------
__global__ __launch_bounds__(256) void sig_kernel(
    const float* __restrict__ ploc, const float* __restrict__ swv,
    const int* __restrict__ maskp, _Float16* __restrict__ sig16)
{
    const int b = blockIdx.y;
    const int l = blockIdx.x;
    const int tid = threadIdx.x;

    __shared__ float pls[512 * 5];
    __shared__ float sws[72];
    __shared__ int   msk[512];

    const float* src = ploc + (size_t)(b * 512 + l) * 512 * 5;
    for (int i = tid; i < 640; i += 256)
        *(float4*)&pls[i * 4] = *(const float4*)(src + i * 4);
    if (tid < 72) sws[tid] = swv[(size_t)(b * 512 + l) * NSW_ + tid];
    for (int i = tid; i < 512; i += 256) msk[i] = maskp[b * 512 + i];
    __syncthreads();

    for (int e = tid; e < H_ * 512; e += 256) {
        const int t  = e & 511;
        const int hh = e >> 9;
        float s = sws[hh * 6];
#pragma unroll
        for (int d = 0; d < SD_; d++) s += sws[hh * 6 + 1 + d] * pls[t * 5 + d];
        const float sig = msk[t] ? 0.f : fmaxf(1.f / (1.f + __expf(-s)), 1e-6f);
        sig16[(((size_t)hh * B_ + b) * 512 + l) * 512 + t] = (_Float16)sig;
    }
}

// ---------------------------------------------------------------------------
// MFMA attention. Block = (h, b, 64-l-tile); iterates 64-wide t-tiles.
// QK: split-bf16 3-term (K=192 effective). P -> LDS (padded) -> A-frag for PV
// (3-term vs split V^T). Row sums accumulate during the coalesced fused-store.
// XCD-swizzled so the 8 l-tiles sharing one (h,b) K/V land on one XCD.
// ---------------------------------------------------------------------------
__global__ __launch_bounds__(256) void attn_kernel(
    const ushort_t* __restrict__ qs2, const ushort_t* __restrict__ ks2,
    const ushort_t* __restrict__ vt2, const _Float16* __restrict__ sig16,
    float* __restrict__ fused, ushort_t* __restrict__ outp2,
    float* __restrict__ sums)
{
    // grid (8,8,12) = 768 blocks; bijective XCD swizzle, x (l-tile) fastest.
    const int flat  = blockIdx.x + 8 * (blockIdx.y + 8 * blockIdx.z);
    const int flat2 = (flat & 7) * 96 + (flat >> 3);
    const int h  = flat2 / 64;
    const int b  = (flat2 >> 3) & 7;
    const int l0 = (flat2 & 7) << 6;

    const int hb = h * B_ + b;
    const int tid  = threadIdx.x;
    const int lane = tid & 63;
    const int wv   = tid >> 6;
    const int l15  = lane & 15;
    const int quad = lane >> 4;

    __shared__ __align__(16) ushort_t qs[64 * 128];
    __shared__ __align__(16) ushort_t ks[64 * 128];
    __shared__ __align__(16) ushort_t vts[128 * 64];
    __shared__ __align__(16) ushort_t ps[64 * 136];   // [l][hi 0-63 | lo 64-127 | pad]
    __shared__ float ssb[4 * 64];
    __shared__ float ssum[64];

    // stage Q tile (swizzled chunks: LDS chunk i holds global chunk (c ^ (r&7)))
    {
        const size_t qbase = ((size_t)hb * 512 + l0) * 128;
#pragma unroll
        for (int j = 0; j < 4; j++) {
            const int i = tid + 256 * j;
            const int r = i >> 4, c = i & 15, gc = c ^ (r & 7);
            gload_lds16(qs2 + qbase + r * 128 + gc * 8, &qs[i * 8]);
        }
    }

    float pacc = 0.f;
    f32x4 accpv[4] = {};

    for (int t0 = 0; t0 < T_; t0 += 64) {
        __syncthreads();
        {
            const size_t kbase = ((size_t)hb * 512 + t0) * 128;
#pragma unroll
            for (int j = 0; j < 4; j++) {
                const int i = tid + 256 * j;
                const int r = i >> 4, c = i & 15, gc = c ^ (r & 7);
                gload_lds16(ks2 + kbase + r * 128 + gc * 8, &ks[i * 8]);
            }
            const size_t vbase = (size_t)hb * 128 * 512;
#pragma unroll
            for (int j = 0; j < 4; j++) {
                const int i = tid + 256 * j;
                const int r = i >> 3, c = i & 7, gc = c ^ (r & 7);
                gload_lds16(vt2 + vbase + (size_t)r * 512 + t0 + gc * 8, &vts[i * 8]);
            }
        }
        __syncthreads();

        // prefetch sig values for this wave's 64x16 S-slice
        float sigv[4][4];
        {
            const _Float16* sgp = sig16 + (((size_t)hb * 512 + l0) * 512) + t0 + wv * 16 + l15;
#pragma unroll
            for (int mt = 0; mt < 4; mt++)
#pragma unroll
                for (int r2 = 0; r2 < 4; r2++)
                    sigv[mt][r2] = (float)sgp[(size_t)(mt * 16 + quad * 4 + r2) * 512];
        }

        // ---- QK: S[64 l x 16 t per wave] ----
        f32x4 acq[4] = {};
        {
            const int trow = wv * 16 + l15;
            const int tsw  = trow & 7;
            const bf16x8 bk0 = *(const bf16x8*)&ks[trow * 128 + ((0  + quad) ^ tsw) * 8];
            const bf16x8 bk1 = *(const bf16x8*)&ks[trow * 128 + ((4  + quad) ^ tsw) * 8];
            const bf16x8 bk2 = *(const bf16x8*)&ks[trow * 128 + ((8  + quad) ^ tsw) * 8];
            const bf16x8 bk3 = *(const bf16x8*)&ks[trow * 128 + ((12 + quad) ^ tsw) * 8];
#pragma unroll
            for (int mt = 0; mt < 4; mt++) {
                const int arow = mt * 16 + l15;
                const int asw  = arow & 7;
                const bf16x8 a0 = *(const bf16x8*)&qs[arow * 128 + ((0  + quad) ^ asw) * 8];
                const bf16x8 a1 = *(const bf16x8*)&qs[arow * 128 + ((4  + quad) ^ asw) * 8];
                const bf16x8 a2 = *(const bf16x8*)&qs[arow * 128 + ((8  + quad) ^ asw) * 8];
                const bf16x8 a3 = *(const bf16x8*)&qs[arow * 128 + ((12 + quad) ^ asw) * 8];
                f32x4 a = acq[mt];
                a = __builtin_amdgcn_mfma_f32_16x16x32_bf16(a0, bk0, a, 0, 0, 0); // hi.hi
                a = __builtin_amdgcn_mfma_f32_16x16x32_bf16(a1, bk1, a, 0, 0, 0);
                a = __builtin_amdgcn_mfma_f32_16x16x32_bf16(a0, bk2, a, 0, 0, 0); // hi.lo
                a = __builtin_amdgcn_mfma_f32_16x16x32_bf16(a1, bk3, a, 0, 0, 0);
                a = __builtin_amdgcn_mfma_f32_16x16x32_bf16(a2, bk0, a, 0, 0, 0); // lo.hi
                a = __builtin_amdgcn_mfma_f32_16x16x32_bf16(a3, bk1, a, 0, 0, 0);
                acq[mt] = a;
            }
        }

        // ---- p = sig * exp(qk/8), split to LDS ----
        {
            const int tcol = wv * 16 + l15;
#pragma unroll
            for (int mt = 0; mt < 4; mt++)
#pragma unroll
                for (int r2 = 0; r2 < 4; r2++) {
                    const int lrow = mt * 16 + quad * 4 + r2;
                    const float p  = sigv[mt][r2] * __expf(acq[mt][r2] * 0.125f);
                    const ushort_t hi = f2bf(p);
                    const ushort_t lo = f2bf(p - bf2f(hi));
                    ps[lrow * 136 + tcol]      = hi;
                    ps[lrow * 136 + 64 + tcol] = lo;
                }
        }
        __syncthreads();

        // ---- fused store (coalesced) + row-sum partials ----
        {
            const int row = tid >> 2, c4 = tid & 3;
            float vbuf[16];
            float s = 0.f;
#pragma unroll
            for (int jj = 0; jj < 16; jj++) {
                const int t = c4 * 16 + jj;
                const float pv = bf2f(ps[row * 136 + t]) + bf2f(ps[row * 136 + 64 + t]);
                vbuf[jj] = pv;
                s += pv;
            }
            pacc += s;
            float* dstf = fused + ((size_t)hb * 512 + l0 + row) * 512 + t0 + c4 * 16;
#pragma unroll
            for (int jj = 0; jj < 4; jj++)
                *(float4*)(dstf + jj * 4) = *(float4*)&vbuf[jj * 4];
        }

        // ---- PV: out[64 l x 16 d per wave] += P * V ----
        {
            const int vrh = wv * 16 + l15;
            const int vrl = 64 + vrh;
            const int swh = vrh & 7, swl = vrl & 7;
            const bf16x8 bh0 = *(const bf16x8*)&vts[vrh * 64 + ((0 + quad) ^ swh) * 8];
            const bf16x8 bh1 = *(const bf16x8*)&vts[vrh * 64 + ((4 + quad) ^ swh) * 8];
            const bf16x8 bl0 = *(const bf16x8*)&vts[vrl * 64 + ((0 + quad) ^ swl) * 8];
            const bf16x8 bl1 = *(const bf16x8*)&vts[vrl * 64 + ((4 + quad) ^ swl) * 8];
#pragma unroll
            for (int mt = 0; mt < 4; mt++) {
                const int prow = mt * 16 + l15;
                const bf16x8 ph0 = *(const bf16x8*)&ps[prow * 136 + 0  + quad * 8];
                const bf16x8 ph1 = *(const bf16x8*)&ps[prow * 136 + 32 + quad * 8];
                const bf16x8 pl0 = *(const bf16x8*)&ps[prow * 136 + 64 + quad * 8];
                const bf16x8 pl1 = *(const bf16x8*)&ps[prow * 136 + 96 + quad * 8];
                f32x4 a = accpv[mt];
                a = __builtin_amdgcn_mfma_f32_16x16x32_bf16(ph0, bh0, a, 0, 0, 0); // Phi.Vhi
                a = __builtin_amdgcn_mfma_f32_16x16x32_bf16(ph1, bh1, a, 0, 0, 0);
                a = __builtin_amdgcn_mfma_f32_16x16x32_bf16(ph0, bl0, a, 0, 0, 0); // Phi.Vlo
                a = __builtin_amdgcn_mfma_f32_16x16x32_bf16(ph1, bl1, a, 0, 0, 0);
                a = __builtin_amdgcn_mfma_f32_16x16x32_bf16(pl0, bh0, a, 0, 0, 0); // Plo.Vhi
                a = __builtin_amdgcn_mfma_f32_16x16x32_bf16(pl1, bh1, a, 0, 0, 0);
                accpv[mt] = a;
            }
        }
    }

    __syncthreads();
    ssb[(tid & 3) * 64 + (tid >> 2)] = pacc;
    __syncthreads();
    if (tid < 64) {
        const float s = ssb[tid] + ssb[64 + tid] + ssb[128 + tid] + ssb[192 + tid];
        ssum[tid] = s;
        sums[(size_t)hb * 512 + l0 + tid] = s;
    }
    __syncthreads();

#pragma unroll
    for (int mt = 0; mt < 4; mt++)
#pragma unroll
        for (int r2 = 0; r2 < 4; r2++) {
            const int lrow = mt * 16 + quad * 4 + r2;
            const float val = accpv[mt][r2] / ssum[lrow];
            const ushort_t hi = f2bf(val);
            const ushort_t lo = f2bf(val - bf2f(hi));
            const size_t obase = ((size_t)(b * 512 + l0 + lrow)) * K2_ + h * 64 + wv * 16 + l15;
            outp2[obase]       = hi;
            outp2[obase + D_]  = lo;
        }
}

// Scale fused_attn in place by 1/rowsum.
__global__ __launch_bounds__(256) void norm_kernel(
    float* __restrict__ fused, const float* __restrict__ sums)
{
    const int gi = blockIdx.x * 256 + threadIdx.x;
    float4* f4 = (float4*)fused;
    float4 v = f4[gi];
    const float inv = 1.f / sums[gi >> 7];
    v.x *= inv; v.y *= inv; v.z *= inv; v.w *= inv;
    f4[gi] = v;
}

// ---------------------------------------------------------------------------
extern "C" void kernel_launch(void* const* d_in, const int* in_sizes, int n_in,
                              void* d_out, int out_size, void* d_ws, size_t ws_size,
                              hipStream_t stream) {
    const float* q    = (const float*)d_in[0];
    const float* k    = (const float*)d_in[1];
    const float* v    = (const float*)d_in[2];
    const float* ploc = (const float*)d_in[3];
    const int*   mask = (const int*)  d_in[4];
    const float* Wq   = (const float*)d_in[5];
    const float* bq   = (const float*)d_in[6];
    const float* Wk   = (const float*)d_in[7];
    const float* bk   = (const float*)d_in[8];
    const float* Wv   = (const float*)d_in[9];
    const float* bv   = (const float*)d_in[10];
    const float* Wl   = (const float*)d_in[11];
    const float* bl   = (const float*)d_in[12];
    const float* Wf   = (const float*)d_in[13];
    const float* bf   = (const float*)d_in[14];

    // Arena. sig16 (50.33 MB) overlays [q2..WlT3 + gap] which are dead after
    // the projection GEMMs. WfT3 and later regions stay live.
    char* base = (char*)d_ws;
    short*    q2    = (short*)(base + 0);            // 12,582,912 B
    short*    k2    = (short*)(base + 12582912);
    short*    v2    = (short*)(base + 25165824);
    short*    WqT3  = (short*)(base + 37748736);     //  3,538,944 B
    short*    WkT3  = (short*)(base + 41287680);
    short*    WvT3  = (short*)(base + 44826624);
    short*    WlT3  = (short*)(base + 48365568);     //    589,824 B
    _Float16* sig16 = (_Float16*)(base + 0);         // 50,331,648 B overlay
    short*    WfT3  = (short*)(base + 50331648);
    ushort_t* qs2a  = (ushort_t*)(base + 53870592);  // 12,582,912 B
    ushort_t* ks2a  = (ushort_t*)(base + 66453504);
    ushort_t* vt2   = (ushort_t*)(base + 79036416);
    float*    swv   = (float*)(base + 91619328);     //  1,179,648 B
    float*    sums  = (float*)(base + 92798976);     //    196,608 B
    short*    outp2 = (short*)(base + 92995584);     // 12,582,912 B -> 105,578,496 total

    float* out   = (float*)d_out;
    float* fused = out + (size_t)4096 * D_;

    asplit_kernel<<<dim3(3, 4096, 3), 256, 0, stream>>>(q, k, v, q2, k2, v2);
    wsplit_kernel<<<dim3(12, 12, 5), 256, 0, stream>>>(
        Wq, Wk, Wv, Wl, Wf, WqT3, WkT3, WvT3, WlT3, WfT3);

    mfma_gemm<<<dim3(6, 32, 4), 256, 0, stream>>>(
        q2, k2, v2, WqT3, WkT3, WvT3, WlT3, WfT3,
        bq, bk, bv, bl, bf, outp2, qs2a, ks2a, vt2, swv, out, 0);

    sig_kernel<<<dim3(512, 8), 256, 0, stream>>>(ploc, swv, mask, sig16);

    attn_kernel<<<dim3(8, 8, 12), 256, 0, stream>>>(
        qs2a, ks2a, vt2, sig16, fused, (ushort_t*)outp2, sums);

    norm_kernel<<<dim3(24576), 256, 0, stream>>>(fused, sums);

    mfma_gemm<<<dim3(6, 32, 1), 256, 0, stream>>>(
        q2, k2, v2, WqT3, WkT3, WvT3, WlT3, WfT3,
        bq, bk, bv, bl, bf, outp2, qs2a, ks2a, vt2, swv, out, 4);
}

// Round 5
// 441.293 us; speedup vs baseline: 1.1729x; 1.0201x over previous
//
#include <hip/hip_runtime.h>
#include <hip/hip_bf16.h>

#define B_ 8
#define L_ 512
#define T_ 512
#define D_ 768
#define H_ 12
#define DH_ 64
#define SD_ 5
#define NSW_ 72   // H*(SD+1)
#define K2_ 1536  // split A:  [hi | lo]
#define K3_ 2304  // split W:  [hi | lo | hi]

typedef __attribute__((ext_vector_type(8))) short bf16x8;
typedef __attribute__((ext_vector_type(4))) float f32x4;
typedef unsigned short ushort_t;

__device__ __forceinline__ unsigned short f2bf(float x) {
    union { __hip_bfloat16 h; unsigned short u; } cv;
    cv.h = __float2bfloat16(x);
    return cv.u;
}
__device__ __forceinline__ float bf2f(unsigned short u) {
    union { unsigned short u; __hip_bfloat16 h; } cv;
    cv.u = u;
    return __bfloat162float(cv.h);
}

__device__ __forceinline__ void gload_lds16(const void* g, void* l) {
    __builtin_amdgcn_global_load_lds((const __attribute__((address_space(1))) void*)g,
                                     (__attribute__((address_space(3))) void*)l,
                                     16, 0, 0);
}

// ---------------------------------------------------------------------------
// Split fp32 activations -> A2 = [hi | lo] bf16, row-major [M][1536].
// ---------------------------------------------------------------------------
__global__ __launch_bounds__(256) void asplit_kernel(
    const float* __restrict__ q, const float* __restrict__ k, const float* __restrict__ v,
    short* __restrict__ q2, short* __restrict__ k2, short* __restrict__ v2)
{
    const int z = blockIdx.z;
    const float* A = (z == 0) ? q : (z == 1) ? k : v;
    short* O = (z == 0) ? q2 : (z == 1) ? k2 : v2;
    const int col = blockIdx.x * 256 + threadIdx.x;
    const int m   = blockIdx.y;
    if (col >= D_) return;
    const float a = A[(size_t)m * D_ + col];
    const unsigned short hi = f2bf(a);
    const unsigned short lo = f2bf(a - bf2f(hi));
    O[(size_t)m * K2_ + col]       = (short)hi;
    O[(size_t)m * K2_ + D_ + col]  = (short)lo;
}

// ---------------------------------------------------------------------------
// Transpose + split weights -> WT3 [Npad x 2304]: row n = [hi | lo | hi].
// ---------------------------------------------------------------------------
__global__ __launch_bounds__(256) void wsplit_kernel(
    const float* __restrict__ Wq, const float* __restrict__ Wk,
    const float* __restrict__ Wv, const float* __restrict__ Wl,
    const float* __restrict__ Wf,
    short* __restrict__ WqT3, short* __restrict__ WkT3, short* __restrict__ WvT3,
    short* __restrict__ WlT3, short* __restrict__ WfT3)
{
    const int z = blockIdx.z;
    const float* W; short* O; int Nw, Npad;
    if (z == 0)      { W = Wq; O = WqT3; Nw = D_;   Npad = 768; }
    else if (z == 1) { W = Wk; O = WkT3; Nw = D_;   Npad = 768; }
    else if (z == 2) { W = Wv; O = WvT3; Nw = D_;   Npad = 768; }
    else if (z == 3) { W = Wl; O = WlT3; Nw = NSW_; Npad = 128; }
    else             { W = Wf; O = WfT3; Nw = D_;   Npad = 768; }

    const int k0 = blockIdx.x * 64;
    const int n0 = blockIdx.y * 64;
    if (n0 >= Npad) return;

    __shared__ float sm[64][65];
    const int c  = threadIdx.x & 63;
    const int r4 = threadIdx.x >> 6;

#pragma unroll
    for (int i = 0; i < 16; i++) {
        const int r = i * 4 + r4;
        float val = 0.f;
        if (n0 + c < Nw) val = W[(size_t)(k0 + r) * Nw + n0 + c];
        sm[r][c] = val;
    }
    __syncthreads();

#pragma unroll
    for (int i = 0; i < 16; i++) {
        const int nl = i * 4 + r4;
        const int n  = n0 + nl;
        if (n >= Npad) continue;
        const float v = (n < Nw) ? sm[c][nl] : 0.f;
        const unsigned short hi = f2bf(v);
        const unsigned short lo = f2bf(v - bf2f(hi));
        const size_t rb = (size_t)n * K3_;
        O[rb + k0 + c]        = (short)hi;
        O[rb + 768 + k0 + c]  = (short)lo;
        O[rb + 1536 + k0 + c] = (short)hi;
    }
}

// ---------------------------------------------------------------------------
// MFMA GEMM (split-bf16, K=2304), BK=64, XOR-swizzled LDS, XCD block swizzle,
// 2-deep double-buffered pipeline with counted vmcnt. Epilogues per z:
//  z=0: qs2a [h][b][l][hi64|lo64]   z=1: ks2a [h][b][t][hi64|lo64]
//  z=2: vt2  [h][b][dd(hi) / 64+dd(lo)][t]   z=3: swv fp32 [4096][72]
//  z=4: out fp32 [4096][768]
// ---------------------------------------------------------------------------
__global__ __launch_bounds__(256) void mfma_gemm(
    const short* __restrict__ q2, const short* __restrict__ k2, const short* __restrict__ v2,
    const short* __restrict__ WqT3, const short* __restrict__ WkT3,
    const short* __restrict__ WvT3, const short* __restrict__ WlT3,
    const short* __restrict__ WfT3,
    const float* __restrict__ bq, const float* __restrict__ bk,
    const float* __restrict__ bv, const float* __restrict__ bl,
    const float* __restrict__ bf,
    const short* __restrict__ outp2,
    ushort_t* __restrict__ qs2a, ushort_t* __restrict__ ks2a, ushort_t* __restrict__ vt2,
    float* __restrict__ swv, float* __restrict__ outf,
    int zoff)
{
    const int nwg   = gridDim.x * gridDim.y * gridDim.z;
    const int flat  = blockIdx.x + gridDim.x * (blockIdx.y + gridDim.y * blockIdx.z);
    const int flat2 = (flat & 7) * (nwg >> 3) + (flat >> 3);
    const int bxg   = flat2 % 6;
    const int rem   = flat2 / 6;
    const int byg   = rem & 31;
    const int bzg   = rem >> 5;

    const int z = zoff + bzg;
    const short* A2; const short* WT3; const float* bias;
    if (z == 0)      { A2 = q2;    WT3 = WqT3; bias = bq; }
    else if (z == 1) { A2 = k2;    WT3 = WkT3; bias = bk; }
    else if (z == 2) { A2 = v2;    WT3 = WvT3; bias = bv; }
    else if (z == 3) { A2 = q2;    WT3 = WlT3; bias = bl; }
    else             { A2 = outp2; WT3 = WfT3; bias = bf; }

    if (z == 3 && bxg != 0) return;

    const int m0 = byg * 128;
    const int n0 = bxg * 128;

    __shared__ __align__(16) short As[2][128 * 64];
    __shared__ __align__(16) short Bs[2][128 * 64];

    const int tid  = threadIdx.x;
    const int lane = tid & 63;
    const int wv_  = tid >> 6;
    const int wm   = (wv_ & 1) << 6;
    const int wn   = (wv_ >> 1) << 6;
    const int l15  = lane & 15;
    const int quad = lane >> 4;

    f32x4 acc[4][4] = {};

    const int NT = K3_ / 64;   // 36 K-steps

    auto stage = [&](int buf, int kb) {
        const int akb = (kb < 768) ? kb : kb - 768;  // A=[hi|lo]; W=[hi|lo|hi]
#pragma unroll
        for (int j = 0; j < 4; j++) {
            const int i = tid + 256 * j;
            const int r = i >> 3, c = i & 7, gc = c ^ (r & 7);
            gload_lds16(A2 + (size_t)(m0 + r) * K2_ + akb + gc * 8, &As[buf][i * 8]);
        }
#pragma unroll
        for (int j = 0; j < 4; j++) {
            const int i = tid + 256 * j;
            const int r = i >> 3, c = i & 7, gc = c ^ (r & 7);
            gload_lds16(WT3 + (size_t)(n0 + r) * K3_ + kb + gc * 8, &Bs[buf][i * 8]);
        }
    };

    stage(0, 0);
    stage(1, 64);

    int cur = 0;
    for (int t = 0; t < NT; ++t) {
        asm volatile("s_waitcnt vmcnt(8)" ::: "memory");
        __builtin_amdgcn_s_barrier();

        bf16x8 af[2][4], bfr[2][4];
#pragma unroll
        for (int kk = 0; kk < 2; kk++)
#pragma unroll
            for (int tt = 0; tt < 4; tt++) {
                const int ar = wm + tt * 16 + l15;
                const int br = wn + tt * 16 + l15;
                af[kk][tt]  = *(const bf16x8*)&As[cur][ar * 64 + (((kk << 2) + quad) ^ (ar & 7)) * 8];
                bfr[kk][tt] = *(const bf16x8*)&Bs[cur][br * 64 + (((kk << 2) + quad) ^ (br & 7)) * 8];
            }
        asm volatile("s_waitcnt lgkmcnt(0)" ::: "memory");
        __builtin_amdgcn_sched_barrier(0);
        __builtin_amdgcn_s_barrier();

        const int kb2 = (t + 2 < NT) ? (t + 2) * 64 : 0;
        stage(cur, kb2);
        __builtin_amdgcn_sched_barrier(0);

#pragma unroll
        for (int kk = 0; kk < 2; kk++)
#pragma unroll
            for (int mt = 0; mt < 4; mt++)
#pragma unroll
                for (int nt = 0; nt < 4; nt++)
                    acc[mt][nt] = __builtin_amdgcn_mfma_f32_16x16x32_bf16(
                        af[kk][mt], bfr[kk][nt], acc[mt][nt], 0, 0, 0);
        cur ^= 1;
    }
    asm volatile("s_waitcnt vmcnt(0)" ::: "memory");

    if (z <= 2) {
        ushort_t* dst = (z == 0) ? qs2a : (z == 1) ? ks2a : vt2;
#pragma unroll
        for (int nt = 0; nt < 4; nt++) {
            const int col = n0 + wn + nt * 16 + l15;
            const int hh = col >> 6, dd = col & 63;
            const float bvv = bias[col];
#pragma unroll
            for (int mt = 0; mt < 4; mt++) {
                const int rowb = m0 + wm + mt * 16 + quad * 4;
                if (z < 2) {
#pragma unroll
                    for (int r = 0; r < 4; r++) {
                        const int gr = rowb + r;
                        const int bb = gr >> 9, ll = gr & 511;
                        const float x = acc[mt][nt][r] + bvv;
                        const ushort_t hi = f2bf(x);
                        const ushort_t lo = f2bf(x - bf2f(hi));
                        const size_t base = (((size_t)hh * B_ + bb) * 512 + ll) * 128 + dd;
                        dst[base]      = hi;
                        dst[base + 64] = lo;
                    }
                } else {
                    const int bb = rowb >> 9, tt = rowb & 511;
                    ushort_t hi4[4], lo4[4];
#pragma unroll
                    for (int r = 0; r < 4; r++) {
                        const float x = acc[mt][nt][r] + bvv;
                        hi4[r] = f2bf(x);
                        lo4[r] = f2bf(x - bf2f(hi4[r]));
                    }
                    const size_t base = (((size_t)hh * B_ + bb) * 128 + dd) * 512 + tt;
                    *(ushort4*)&dst[base]            = *(ushort4*)hi4;
                    *(ushort4*)&dst[base + 64 * 512] = *(ushort4*)lo4;
                }
            }
        }
    } else if (z == 3) {
#pragma unroll
        for (int nt = 0; nt < 4; nt++) {
            const int col = n0 + wn + nt * 16 + l15;
            if (col >= NSW_) continue;
            const float bvv = bias[col];
#pragma unroll
            for (int mt = 0; mt < 4; mt++) {
                const int row = m0 + wm + mt * 16 + quad * 4;
#pragma unroll
                for (int r = 0; r < 4; r++)
                    swv[(size_t)(row + r) * NSW_ + col] = acc[mt][nt][r] + bvv;
            }
        }
    } else {
#pragma unroll
        for (int nt = 0; nt < 4; nt++) {
            const int col = n0 + wn + nt * 16 + l15;
            const float bvv = bias[col];
#pragma unroll
            for (int mt = 0; mt < 4; mt++) {
                const int row = m0 + wm + mt * 16 + quad * 4;
#pragma unroll
                for (int r = 0; r < 4; r++)
                    outf[(size_t)(row + r) * D_ + col] = acc[mt][nt][r] + bvv;
            }
        }
    }
}

// ---------------------------------------------------------------------------
// sig16[h][b][l][t] = mask ? 0 : max(sigmoid(bias_h + w_h · ploc[b,l,t,:]), 1e-6)
// ---------------------------------------------------------------------------
__global__ __launch_bounds__(256) void sig_kernel(
    const float* __restrict__ ploc, const float* __restrict__ swv,
    const int* __restrict__ maskp, _Float16* __restrict__ sig16)
{
    const int b = blockIdx.y;
    const int l = blockIdx.x;
    const int tid = threadIdx.x;

    __shared__ float pls[512 * 5];
    __shared__ float sws[72];
    __shared__ int   msk[512];

    const float* src = ploc + (size_t)(b * 512 + l) * 512 * 5;
    for (int i = tid; i < 640; i += 256)
        *(float4*)&pls[i * 4] = *(const float4*)(src + i * 4);
    if (tid < 72) sws[tid] = swv[(size_t)(b * 512 + l) * NSW_ + tid];
    for (int i = tid; i < 512; i += 256) msk[i] = maskp[b * 512 + i];
    __syncthreads();

    for (int e = tid; e < H_ * 512; e += 256) {
        const int t  = e & 511;
        const int hh = e >> 9;
        float s = sws[hh * 6];
#pragma unroll
        for (int d = 0; d < SD_; d++) s += sws[hh * 6 + 1 + d] * pls[t * 5 + d];
        const float sig = msk[t] ? 0.f : fmaxf(1.f / (1.f + __expf(-s)), 1e-6f);
        sig16[(((size_t)hh * B_ + b) * 512 + l) * 512 + t] = (_Float16)sig;
    }
}

// ---------------------------------------------------------------------------
// MFMA attention v2 — pipelined. Q in registers; K double-buffered (counted
// vmcnt(4), staged one iter ahead); V single-buffer staged at iter-top and
// drained at the mid-barrier; raw s_barriers (no vmcnt(0) in the loop).
// ps stride 152 (19 chunks, odd) -> conflict-free b128 reads.
// ---------------------------------------------------------------------------
__global__ __launch_bounds__(256) void attn_kernel(
    const ushort_t* __restrict__ qs2, const ushort_t* __restrict__ ks2,
    const ushort_t* __restrict__ vt2, const _Float16* __restrict__ sig16,
    float* __restrict__ fused, ushort_t* __restrict__ outp2,
    float* __restrict__ sums)
{
    // grid (8,8,12) = 768 blocks; bijective XCD swizzle, x (l-tile) fastest.
    const int flat  = blockIdx.x + 8 * (blockIdx.y + 8 * blockIdx.z);
    const int flat2 = (flat & 7) * 96 + (flat >> 3);
    const int h  = flat2 / 64;
    const int b  = (flat2 >> 3) & 7;
    const int l0 = (flat2 & 7) << 6;

    const int hb = h * B_ + b;
    const int tid  = threadIdx.x;
    const int lane = tid & 63;
    const int wv   = tid >> 6;
    const int l15  = lane & 15;
    const int quad = lane >> 4;

    __shared__ __align__(16) ushort_t ks[2][64 * 128];
    __shared__ __align__(16) ushort_t vts[128 * 64];
    __shared__ __align__(16) ushort_t ps[64 * 152];   // [l][hi 0-63 | lo 64-127 | pad]; stride 19 chunks
    __shared__ float ssb[4 * 64];
    __shared__ float ssum[64];

    // Q fragments straight to registers (16 x 16B loads; chunks quad,4+q,8+q,12+q)
    bf16x8 qreg[4][4];
    {
        const ushort_t* qb = qs2 + ((size_t)hb * 512 + l0) * 128;
#pragma unroll
        for (int mt = 0; mt < 4; mt++) {
            const ushort_t* qr = qb + (size_t)(mt * 16 + l15) * 128 + quad * 8;
            qreg[mt][0] = *(const bf16x8*)(qr);
            qreg[mt][1] = *(const bf16x8*)(qr + 32);
            qreg[mt][2] = *(const bf16x8*)(qr + 64);
            qreg[mt][3] = *(const bf16x8*)(qr + 96);
        }
    }

    float pacc = 0.f;
    f32x4 accpv[4] = {};

    auto stageK = [&](int buf, int t0s) {
        const size_t kbase = ((size_t)hb * 512 + t0s) * 128;
#pragma unroll
        for (int j = 0; j < 4; j++) {
            const int i = tid + 256 * j;
            const int r = i >> 4, c = i & 15, gc = c ^ (r & 7);
            gload_lds16(ks2 + kbase + r * 128 + gc * 8, &ks[buf][i * 8]);
        }
    };
    auto stageV = [&](int t0s) {
        const size_t vbase = (size_t)hb * 128 * 512;
#pragma unroll
        for (int j = 0; j < 4; j++) {
            const int i = tid + 256 * j;
            const int r = i >> 3, c = i & 7, gc = c ^ (r & 7);
            gload_lds16(vt2 + vbase + (size_t)r * 512 + t0s + gc * 8, &vts[i * 8]);
        }
    };

    stageK(0, 0);

#pragma unroll 1
    for (int it = 0; it < 8; ++it) {
        const int t0  = it << 6;
        const int cur = it & 1;
        // K(it) landed: at it=0 only K0 is outstanding; later, K(it)[4, oldest]
        // + fused stores(it-1)[4] are outstanding.
        if (it == 0) asm volatile("s_waitcnt vmcnt(0)" ::: "memory");
        else         asm volatile("s_waitcnt vmcnt(4)" ::: "memory");
        __builtin_amdgcn_sched_barrier(0);
        __builtin_amdgcn_s_barrier();   // everyone's K(it) visible; prev-iter LDS reads done

        // sig loads FIRST (oldest of this iter's vmem) so the split-phase wait
        // on sigv leaves the V/K staging loads in flight.
        float sigv[4][4];
        {
            const _Float16* sgp = sig16 + (((size_t)hb * 512 + l0) * 512) + t0 + wv * 16 + l15;
#pragma unroll
            for (int mt = 0; mt < 4; mt++)
#pragma unroll
                for (int r2 = 0; r2 < 4; r2++)
                    sigv[mt][r2] = (float)sgp[(size_t)(mt * 16 + quad * 4 + r2) * 512];
        }
        __builtin_amdgcn_sched_barrier(0);
        stageV(t0);                                   // V(it): drained at mid-barrier
        stageK(cur ^ 1, (it < 7) ? t0 + 64 : 0);      // K(it+1): drained next iter-top
        __builtin_amdgcn_sched_barrier(0);

        // ---- QK: S[64 l x 16 t per wave] ----
        f32x4 acq[4] = {};
        {
            const int trow = wv * 16 + l15;
            const int tsw  = trow & 7;
            const bf16x8 bk0 = *(const bf16x8*)&ks[cur][trow * 128 + ((0  + quad) ^ tsw) * 8];
            const bf16x8 bk1 = *(const bf16x8*)&ks[cur][trow * 128 + ((4  + quad) ^ tsw) * 8];
            const bf16x8 bk2 = *(const bf16x8*)&ks[cur][trow * 128 + ((8  + quad) ^ tsw) * 8];
            const bf16x8 bk3 = *(const bf16x8*)&ks[cur][trow * 128 + ((12 + quad) ^ tsw) * 8];
#pragma unroll
            for (int mt = 0; mt < 4; mt++) {
                f32x4 a = acq[mt];
                a = __builtin_amdgcn_mfma_f32_16x16x32_bf16(qreg[mt][0], bk0, a, 0, 0, 0); // hi.hi
                a = __builtin_amdgcn_mfma_f32_16x16x32_bf16(qreg[mt][1], bk1, a, 0, 0, 0);
                a = __builtin_amdgcn_mfma_f32_16x16x32_bf16(qreg[mt][0], bk2, a, 0, 0, 0); // hi.lo
                a = __builtin_amdgcn_mfma_f32_16x16x32_bf16(qreg[mt][1], bk3, a, 0, 0, 0);
                a = __builtin_amdgcn_mfma_f32_16x16x32_bf16(qreg[mt][2], bk0, a, 0, 0, 0); // lo.hi
                a = __builtin_amdgcn_mfma_f32_16x16x32_bf16(qreg[mt][3], bk1, a, 0, 0, 0);
                acq[mt] = a;
            }
        }

        // ---- p = sig * exp(qk/8), split to LDS ----
        {
            const int tcol = wv * 16 + l15;
#pragma unroll
            for (int mt = 0; mt < 4; mt++)
#pragma unroll
                for (int r2 = 0; r2 < 4; r2++) {
                    const int lrow = mt * 16 + quad * 4 + r2;
                    const float p  = sigv[mt][r2] * __expf(acq[mt][r2] * 0.125f);
                    const ushort_t hi = f2bf(p);
                    const ushort_t lo = f2bf(p - bf2f(hi));
                    ps[lrow * 152 + tcol]      = hi;
                    ps[lrow * 152 + 64 + tcol] = lo;
                }
        }
        // ps writes visible + V(it) landed; K(it+1) (4 loads) stays in flight.
        asm volatile("s_waitcnt lgkmcnt(0) vmcnt(4)" ::: "memory");
        __builtin_amdgcn_sched_barrier(0);
        __builtin_amdgcn_s_barrier();

        // ---- fused store (b128 ps reads) + row-sum partials ----
        {
            const int row = tid >> 2, c4 = tid & 3;
            const bf16x8 h0 = *(const bf16x8*)&ps[row * 152 + c4 * 16];
            const bf16x8 h1 = *(const bf16x8*)&ps[row * 152 + c4 * 16 + 8];
            const bf16x8 g0 = *(const bf16x8*)&ps[row * 152 + 64 + c4 * 16];
            const bf16x8 g1 = *(const bf16x8*)&ps[row * 152 + 64 + c4 * 16 + 8];
            float vbuf[16];
            float s = 0.f;
#pragma unroll
            for (int jj = 0; jj < 8; jj++) {
                vbuf[jj]     = bf2f((ushort_t)h0[jj]) + bf2f((ushort_t)g0[jj]);
                vbuf[8 + jj] = bf2f((ushort_t)h1[jj]) + bf2f((ushort_t)g1[jj]);
                s += vbuf[jj] + vbuf[8 + jj];
            }
            pacc += s;
            float* dstf = fused + ((size_t)hb * 512 + l0 + row) * 512 + t0 + c4 * 16;
#pragma unroll
            for (int jj = 0; jj < 4; jj++)
                *(float4*)(dstf + jj * 4) = *(float4*)&vbuf[jj * 4];
        }

        // ---- PV: out[64 l x 16 d per wave] += P * V ----
        {
            const int vrh = wv * 16 + l15;
            const int vrl = 64 + vrh;
            const int swh = vrh & 7, swl = vrl & 7;
            const bf16x8 bh0 = *(const bf16x8*)&vts[vrh * 64 + ((0 + quad) ^ swh) * 8];
            const bf16x8 bh1 = *(const bf16x8*)&vts[vrh * 64 + ((4 + quad) ^ swh) * 8];
            const bf16x8 bl0 = *(const bf16x8*)&vts[vrl * 64 + ((0 + quad) ^ swl) * 8];
            const bf16x8 bl1 = *(const bf16x8*)&vts[vrl * 64 + ((4 + quad) ^ swl) * 8];
#pragma unroll
            for (int mt = 0; mt < 4; mt++) {
                const int prow = mt * 16 + l15;
                const bf16x8 ph0 = *(const bf16x8*)&ps[prow * 152 + 0  + quad * 8];
                const bf16x8 ph1 = *(const bf16x8*)&ps[prow * 152 + 32 + quad * 8];
                const bf16x8 pl0 = *(const bf16x8*)&ps[prow * 152 + 64 + quad * 8];
                const bf16x8 pl1 = *(const bf16x8*)&ps[prow * 152 + 96 + quad * 8];
                f32x4 a = accpv[mt];
                a = __builtin_amdgcn_mfma_f32_16x16x32_bf16(ph0, bh0, a, 0, 0, 0); // Phi.Vhi
                a = __builtin_amdgcn_mfma_f32_16x16x32_bf16(ph1, bh1, a, 0, 0, 0);
                a = __builtin_amdgcn_mfma_f32_16x16x32_bf16(ph0, bl0, a, 0, 0, 0); // Phi.Vlo
                a = __builtin_amdgcn_mfma_f32_16x16x32_bf16(ph1, bl1, a, 0, 0, 0);
                a = __builtin_amdgcn_mfma_f32_16x16x32_bf16(pl0, bh0, a, 0, 0, 0); // Plo.Vhi
                a = __builtin_amdgcn_mfma_f32_16x16x32_bf16(pl1, bh1, a, 0, 0, 0);
                accpv[mt] = a;
            }
        }
    }
    asm volatile("s_waitcnt vmcnt(0)" ::: "memory");   // drain dummy K(8)

    __syncthreads();
    ssb[(tid & 3) * 64 + (tid >> 2)] = pacc;
    __syncthreads();
    if (tid < 64) {
        const float s = ssb[tid] + ssb[64 + tid] + ssb[128 + tid] + ssb[192 + tid];
        ssum[tid] = s;
        sums[(size_t)hb * 512 + l0 + tid] = s;
    }
    __syncthreads();

#pragma unroll
    for (int mt = 0; mt < 4; mt++)
#pragma unroll
        for (int r2 = 0; r2 < 4; r2++) {
            const int lrow = mt * 16 + quad * 4 + r2;
            const float val = accpv[mt][r2] / ssum[lrow];
            const ushort_t hi = f2bf(val);
            const ushort_t lo = f2bf(val - bf2f(hi));
            const size_t obase = ((size_t)(b * 512 + l0 + lrow)) * K2_ + h * 64 + wv * 16 + l15;
            outp2[obase]       = hi;
            outp2[obase + D_]  = lo;
        }
}

// Scale fused_attn in place by 1/rowsum.
__global__ __launch_bounds__(256) void norm_kernel(
    float* __restrict__ fused, const float* __restrict__ sums)
{
    const int gi = blockIdx.x * 256 + threadIdx.x;
    float4* f4 = (float4*)fused;
    float4 v = f4[gi];
    const float inv = 1.f / sums[gi >> 7];
    v.x *= inv; v.y *= inv; v.z *= inv; v.w *= inv;
    f4[gi] = v;
}

// ---------------------------------------------------------------------------
extern "C" void kernel_launch(void* const* d_in, const int* in_sizes, int n_in,
                              void* d_out, int out_size, void* d_ws, size_t ws_size,
                              hipStream_t stream) {
    const float* q    = (const float*)d_in[0];
    const float* k    = (const float*)d_in[1];
    const float* v    = (const float*)d_in[2];
    const float* ploc = (const float*)d_in[3];
    const int*   mask = (const int*)  d_in[4];
    const float* Wq   = (const float*)d_in[5];
    const float* bq   = (const float*)d_in[6];
    const float* Wk   = (const float*)d_in[7];
    const float* bk   = (const float*)d_in[8];
    const float* Wv   = (const float*)d_in[9];
    const float* bv   = (const float*)d_in[10];
    const float* Wl   = (const float*)d_in[11];
    const float* bl   = (const float*)d_in[12];
    const float* Wf   = (const float*)d_in[13];
    const float* bf   = (const float*)d_in[14];

    // Arena. sig16 (50.33 MB) overlays [q2..WlT3 + gap] which are dead after
    // the projection GEMMs. WfT3 and later regions stay live.
    char* base = (char*)d_ws;
    short*    q2    = (short*)(base + 0);            // 12,582,912 B
    short*    k2    = (short*)(base + 12582912);
    short*    v2    = (short*)(base + 25165824);
    short*    WqT3  = (short*)(base + 37748736);     //  3,538,944 B
    short*    WkT3  = (short*)(base + 41287680);
    short*    WvT3  = (short*)(base + 44826624);
    short*    WlT3  = (short*)(base + 48365568);     //    589,824 B
    _Float16* sig16 = (_Float16*)(base + 0);         // 50,331,648 B overlay
    short*    WfT3  = (short*)(base + 50331648);
    ushort_t* qs2a  = (ushort_t*)(base + 53870592);  // 12,582,912 B
    ushort_t* ks2a  = (ushort_t*)(base + 66453504);
    ushort_t* vt2   = (ushort_t*)(base + 79036416);
    float*    swv   = (float*)(base + 91619328);     //  1,179,648 B
    float*    sums  = (float*)(base + 92798976);     //    196,608 B
    short*    outp2 = (short*)(base + 92995584);     // 12,582,912 B -> 105,578,496 total

    float* out   = (float*)d_out;
    float* fused = out + (size_t)4096 * D_;

    asplit_kernel<<<dim3(3, 4096, 3), 256, 0, stream>>>(q, k, v, q2, k2, v2);
    wsplit_kernel<<<dim3(12, 12, 5), 256, 0, stream>>>(
        Wq, Wk, Wv, Wl, Wf, WqT3, WkT3, WvT3, WlT3, WfT3);

    mfma_gemm<<<dim3(6, 32, 4), 256, 0, stream>>>(
        q2, k2, v2, WqT3, WkT3, WvT3, WlT3, WfT3,
        bq, bk, bv, bl, bf, outp2, qs2a, ks2a, vt2, swv, out, 0);

    sig_kernel<<<dim3(512, 8), 256, 0, stream>>>(ploc, swv, mask, sig16);

    attn_kernel<<<dim3(8, 8, 12), 256, 0, stream>>>(
        qs2a, ks2a, vt2, sig16, fused, (ushort_t*)outp2, sums);

    norm_kernel<<<dim3(24576), 256, 0, stream>>>(fused, sums);

    mfma_gemm<<<dim3(6, 32, 1), 256, 0, stream>>>(
        q2, k2, v2, WqT3, WkT3, WvT3, WlT3, WfT3,
        bq, bk, bv, bl, bf, outp2, qs2a, ks2a, vt2, swv, out, 4);
}